// Round 2
// baseline (1004.108 us; speedup 1.0000x reference)
//
#include <hip/hip_runtime.h>
#include <hip/hip_bf16.h>

#define N_NODES 50000
#define N_EDGES 600000
#define F 128
#define R 2
#define NLAYER 4
#define NSEG (N_NODES * R)  /* 100000 */
#define NB 384              /* gemm out cols: 256 y + 128 z */
#define BN_EPS 1e-5f
#define BETA 1e-4f

typedef __hip_bfloat16 bf16;
typedef __attribute__((ext_vector_type(8))) short short8;  // 8 bf16 (4 VGPRs)
typedef __attribute__((ext_vector_type(4))) float floatx4; // 4 fp32 acc

// ---------------- weight transpose + f32->bf16: Bt[l][j][d] = W[l][d][j] ----------------
// cols j: [0,128)=W_rel[0], [128,256)=W_rel[1], [256,384)=W_root
__global__ void k_wt(const float* __restrict__ W0_rel, const float* __restrict__ W0_root,
                     const float* __restrict__ Ws_rel, const float* __restrict__ Ws_root,
                     bf16* __restrict__ Bt) {
    int idx = blockIdx.x * 256 + threadIdx.x;
    if (idx >= NLAYER * NB * F) return;
    int l = idx / (NB * F);
    int rem = idx % (NB * F);
    int j = rem / F, d = rem % F;
    float v;
    if (j < 256) {
        int r = j >> 7, c = j & 127;
        v = (l == 0) ? W0_rel[(r * F + d) * F + c]
                     : Ws_rel[((size_t)((l - 1) * R + r) * F + d) * F + c];
    } else {
        int c = j - 256;
        v = (l == 0) ? W0_root[d * F + c]
                     : Ws_root[((size_t)(l - 1) * F + d) * F + c];
    }
    Bt[idx] = __float2bfloat16(v);
}

// ---------------- segment counts ----------------
__global__ void k_count(const int* __restrict__ dst, const int* __restrict__ et,
                        int* __restrict__ cnt) {
    int e = blockIdx.x * 256 + threadIdx.x;
    if (e < N_EDGES) atomicAdd(&cnt[dst[e] * R + et[e]], 1);
}

// ---------------- exclusive scan of cnt (single block) ----------------
#define CHUNK 98  /* ceil(100000/1024) */
__global__ void k_scan(const int* __restrict__ cnt, int* __restrict__ off) {
    __shared__ int tsum[1024];
    int t = threadIdx.x;
    int s0 = t * CHUNK;
    int s = 0;
    for (int i = 0; i < CHUNK; i++) { int g = s0 + i; if (g < NSEG) s += cnt[g]; }
    tsum[t] = s;
    __syncthreads();
    for (int d = 1; d < 1024; d <<= 1) {
        int v = (t >= d) ? tsum[t - d] : 0;
        __syncthreads();
        tsum[t] += v;
        __syncthreads();
    }
    int base = (t == 0) ? 0 : tsum[t - 1];
    for (int i = 0; i < CHUNK; i++) {
        int g = s0 + i;
        if (g < NSEG) { off[g] = base; base += cnt[g]; }
    }
}

// ---------------- fill segment-sorted src list ----------------
__global__ void k_fill(const int* __restrict__ src, const int* __restrict__ dst,
                       const int* __restrict__ et, const int* __restrict__ off,
                       int* __restrict__ fill, int* __restrict__ esrc) {
    int e = blockIdx.x * 256 + threadIdx.x;
    if (e >= N_EDGES) return;
    int seg = dst[e] * R + et[e];
    int idx = off[seg] + atomicAdd(&fill[seg], 1);
    esrc[idx] = src[e];
}

// ---------------- BN column stats: gs[0..127]=sum, gs[128..255]=sumsq ----------------
__global__ void k_bnstats(const float* __restrict__ h, float* __restrict__ gs) {
    int c = threadIdx.x & 127;
    int rl = threadIdx.x >> 7;
    float s = 0.f, q = 0.f;
    for (int r = blockIdx.x * 2 + rl; r < N_NODES; r += gridDim.x * 2) {
        float v = h[(size_t)r * F + c];
        s += v; q += v * v;
    }
    __shared__ float ls[256], lq[256];
    ls[threadIdx.x] = s; lq[threadIdx.x] = q;
    __syncthreads();
    if (rl == 0) {
        atomicAdd(&gs[c], ls[c] + ls[c + 128]);
        atomicAdd(&gs[128 + c], lq[c] + lq[c + 128]);
    }
}

// ---------------- fused BN-apply + GEMM: [y|z] = bn(h) @ [Wr0|Wr1|Wroot] ----------------
// 64x64 tile, 4 waves, full K=128 staged. LDS pad: stride 136 bf16 (2-way = free).
__launch_bounds__(256)
__global__ void k_gemm(const float* __restrict__ h, const float* __restrict__ gs,
                       const bf16* __restrict__ Bt, const float* __restrict__ bias,
                       bf16* __restrict__ y, float* __restrict__ z) {
    __shared__ bf16 As[64 * 136];
    __shared__ bf16 Bs[64 * 136];
    __shared__ float mu_s[128], rs_s[128];
    int t = threadIdx.x;
    if (t < 128) {
        float m = gs[t] * (1.0f / N_NODES);
        float q = gs[128 + t] * (1.0f / N_NODES);
        mu_s[t] = m;
        rs_s[t] = rsqrtf(q - m * m + BN_EPS);
    }
    __syncthreads();
    int m0 = blockIdx.x * 64;
    int n0 = blockIdx.y * 64;
    // stage B tile (Bt rows are output-cols, contiguous K)
    {
        int n = t >> 2;
        int c0 = (t & 3) * 32;
        const bf16* sp = Bt + (size_t)(n0 + n) * F + c0;
        bf16* dp = Bs + n * 136 + c0;
        for (int i = 0; i < 4; i++)
            *(short8*)(dp + i * 8) = *(const short8*)(sp + i * 8);
    }
    // stage A tile with BN applied, f32 -> bf16
    for (int i = 0; i < 32; i++) {
        int idx = t + i * 256;
        int row = idx >> 7, col = idx & 127;
        int m = m0 + row;
        float v = (m < N_NODES) ? h[(size_t)m * F + col] : 0.0f;
        float hb = (v - mu_s[col]) * rs_s[col] + BETA;
        As[row * 136 + col] = __float2bfloat16(hb);
    }
    __syncthreads();
    int w = t >> 6;
    int lane = t & 63;
    int lm = lane & 15;   // A-row / B-col / D-col
    int lq = lane >> 4;   // quad -> k chunk / D-row group
    floatx4 acc[4];
    for (int j = 0; j < 4; j++) acc[j] = (floatx4){0.f, 0.f, 0.f, 0.f};
    for (int ki = 0; ki < 4; ki++) {
        int k = ki * 32 + lq * 8;
        short8 a = *(const short8*)(As + (w * 16 + lm) * 136 + k);
        for (int j = 0; j < 4; j++) {
            short8 b = *(const short8*)(Bs + (j * 16 + lm) * 136 + k);
            acc[j] = __builtin_amdgcn_mfma_f32_16x16x32_bf16(a, b, acc[j], 0, 0, 0);
        }
    }
    // epilogue: D[m][n], m=(lane>>4)*4+reg, n=lane&15 (verified m89 mapping)
    for (int j = 0; j < 4; j++) {
        for (int reg = 0; reg < 4; reg++) {
            int m = m0 + w * 16 + lq * 4 + reg;
            int n = n0 + j * 16 + lm;
            if (m < N_NODES) {
                float v = acc[j][reg];
                if (n < 256) y[(size_t)m * 256 + n] = __float2bfloat16(v);
                else z[(size_t)m * F + (n - 256)] = v + bias[n - 256];
            }
        }
    }
}

// ---------------- per-node pull aggregation + relu + residual ----------------
__global__ void k_aggregate(const bf16* __restrict__ y, const float* __restrict__ z,
                            const int* __restrict__ cnt, const int* __restrict__ off,
                            const int* __restrict__ esrc,
                            float* __restrict__ h, float* __restrict__ outp, int layer) {
    int wid = (blockIdx.x * 256 + threadIdx.x) >> 6;
    int lane = threadIdx.x & 63;
    if (wid >= N_NODES) return;
    int n = wid;
    int f = lane * 2;
    float2 zz = *(const float2*)(z + (size_t)n * F + f);
    float a0 = zz.x, a1 = zz.y;
    for (int r = 0; r < R; r++) {
        int seg = n * R + r;
        int c = cnt[seg];
        if (c > 0) {
            int o = off[seg];
            float s0 = 0.f, s1 = 0.f;
            for (int i = 0; i < c; i++) {
                int sn = esrc[o + i];
                __hip_bfloat162 vv = *(const __hip_bfloat162*)(y + (size_t)sn * 256 + r * F + f);
                s0 += __bfloat162float(vv.x);
                s1 += __bfloat162float(vv.y);
            }
            float inv = 1.0f / (float)c;
            a0 += s0 * inv; a1 += s1 * inv;
        }
    }
    a0 = fmaxf(a0, 0.f);
    a1 = fmaxf(a1, 0.f);
    if (layer > 0) {
        float2 hp = *(const float2*)(h + (size_t)n * F + f);
        a0 += hp.x; a1 += hp.y;
    }
    float2 o2; o2.x = a0; o2.y = a1;
    *(float2*)(h + (size_t)n * F + f) = o2;
    if (outp) {
        float2 q2; q2.x = a0; q2.y = a1;
        *(float2*)(outp + (size_t)n * F + f) = q2;
    }
}

extern "C" void kernel_launch(void* const* d_in, const int* in_sizes, int n_in,
                              void* d_out, int out_size, void* d_ws, size_t ws_size,
                              hipStream_t stream) {
    const float* x       = (const float*)d_in[0];
    const int*   eidx    = (const int*)d_in[1];
    const int*   etype   = (const int*)d_in[2];
    const float* W0_rel  = (const float*)d_in[3];
    const float* W0_root = (const float*)d_in[4];
    const float* b0      = (const float*)d_in[5];
    const float* Ws_rel  = (const float*)d_in[6];
    const float* Ws_root = (const float*)d_in[7];
    const float* bs      = (const float*)d_in[8];
    const int* src = eidx;
    const int* dst = eidx + N_EDGES;

    char* w = (char*)d_ws;
    float* h   = (float*)w; w += (size_t)N_NODES * F * 4;     // 25.6 MB
    float* z   = (float*)w; w += (size_t)N_NODES * F * 4;     // 25.6 MB
    bf16*  y   = (bf16*)w;  w += (size_t)N_NODES * 256 * 2;   // 25.6 MB
    bf16*  Bt  = (bf16*)w;  w += (size_t)NLAYER * NB * F * 2; // 384 KB
    int* cnt   = (int*)w;   w += (size_t)NSEG * 4;            // contiguous zero region:
    int* fill  = (int*)w;   w += (size_t)NSEG * 4;            //   cnt | fill | stats
    float* stats = (float*)w; w += (size_t)NLAYER * 256 * 4;
    int* off   = (int*)w;   w += (size_t)NSEG * 4;
    int* esrc  = (int*)w;   w += (size_t)N_EDGES * 4;         // total ~77 MB

    hipMemsetAsync(cnt, 0, (size_t)NSEG * 4 * 2 + (size_t)NLAYER * 256 * 4, stream);
    k_wt<<<(NLAYER * NB * F + 255) / 256, 256, 0, stream>>>(W0_rel, W0_root, Ws_rel, Ws_root, Bt);
    k_count<<<(N_EDGES + 255) / 256, 256, 0, stream>>>(dst, etype, cnt);
    k_scan<<<1, 1024, 0, stream>>>(cnt, off);
    k_fill<<<(N_EDGES + 255) / 256, 256, 0, stream>>>(src, dst, etype, off, fill, esrc);

    for (int l = 0; l < NLAYER; l++) {
        float* gs = stats + l * 256;
        const float* bias = (l == 0) ? b0 : (bs + (size_t)(l - 1) * F);
        const float* hin = (l == 0) ? x : h;
        k_bnstats<<<512, 256, 0, stream>>>(hin, gs);
        k_gemm<<<dim3((N_NODES + 63) / 64, NB / 64), 256, 0, stream>>>(
            hin, gs, Bt + (size_t)l * NB * F, bias, y, z);
        k_aggregate<<<(N_NODES * 64 + 255) / 256, 256, 0, stream>>>(
            y, z, cnt, off, esrc, h, (l == 3) ? (float*)d_out : nullptr, l);
    }
}

// Round 3
// 823.485 us; speedup vs baseline: 1.2193x; 1.2193x over previous
//
#include <hip/hip_runtime.h>
#include <hip/hip_bf16.h>

#define N_NODES 50000
#define N_EDGES 600000
#define F 128
#define R 2
#define NLAYER 4
#define NSEG (N_NODES * R)  /* 100000 */
#define NSCB 98             /* scan blocks: ceil(100000/1024) */
#define NB 384              /* gemm out cols: 256 y + 128 z */
#define BN_EPS 1e-5f
#define BETA 1e-4f

typedef __hip_bfloat16 bf16;
typedef __attribute__((ext_vector_type(8))) short short8;  // 8 bf16 (4 VGPRs)
typedef __attribute__((ext_vector_type(4))) float floatx4; // 4 fp32 acc

// ---------------- weight transpose + f32->bf16: Bt[l][j][d] = W[l][d][j] ----------------
// cols j: [0,128)=W_rel[0], [128,256)=W_rel[1], [256,384)=W_root
__global__ void k_wt(const float* __restrict__ W0_rel, const float* __restrict__ W0_root,
                     const float* __restrict__ Ws_rel, const float* __restrict__ Ws_root,
                     bf16* __restrict__ Bt) {
    int idx = blockIdx.x * 256 + threadIdx.x;
    if (idx >= NLAYER * NB * F) return;
    int l = idx / (NB * F);
    int rem = idx % (NB * F);
    int j = rem / F, d = rem % F;
    float v;
    if (j < 256) {
        int r = j >> 7, c = j & 127;
        v = (l == 0) ? W0_rel[(r * F + d) * F + c]
                     : Ws_rel[((size_t)((l - 1) * R + r) * F + d) * F + c];
    } else {
        int c = j - 256;
        v = (l == 0) ? W0_root[d * F + c]
                     : Ws_root[((size_t)(l - 1) * F + d) * F + c];
    }
    Bt[idx] = __float2bfloat16(v);
}

// ---------------- segment counts ----------------
__global__ void k_count(const int* __restrict__ dst, const int* __restrict__ et,
                        int* __restrict__ cnt) {
    int e = blockIdx.x * 256 + threadIdx.x;
    if (e < N_EDGES) atomicAdd(&cnt[dst[e] * R + et[e]], 1);
}

// ---------------- multi-block exclusive scan of cnt ----------------
// phase 1: per-block scan (coalesced), write exclusive offsets + block total
__global__ void k_scan1(const int* __restrict__ cnt, int* __restrict__ off,
                        int* __restrict__ bsum) {
    int t = threadIdx.x;
    int g = blockIdx.x * 1024 + t;
    int v = (g < NSEG) ? cnt[g] : 0;
    int lane = t & 63;
    int wv = t >> 6;
    int x = v;
    for (int d = 1; d < 64; d <<= 1) {
        int y = __shfl_up(x, d, 64);
        if (lane >= d) x += y;
    }
    __shared__ int wtot[16];
    if (lane == 63) wtot[wv] = x;
    __syncthreads();
    if (t < 16) {
        int s = wtot[t];
        for (int d = 1; d < 16; d <<= 1) {
            int y = __shfl_up(s, d, 64);
            if (t >= d) s += y;
        }
        wtot[t] = s;
    }
    __syncthreads();
    int wpre = (wv == 0) ? 0 : wtot[wv - 1];
    int incl = x + wpre;
    if (g < NSEG) off[g] = incl - v;  // exclusive within block
    if (t == 1023) bsum[blockIdx.x] = incl;
}

// phase 2: exclusive scan of the 98 block totals (single tiny block)
__global__ void k_scan2(int* __restrict__ bsum) {
    __shared__ int s[128];
    int t = threadIdx.x;
    int v = (t < NSCB) ? bsum[t] : 0;
    s[t] = v;
    __syncthreads();
    for (int d = 1; d < 128; d <<= 1) {
        int y = (t >= d) ? s[t - d] : 0;
        __syncthreads();
        s[t] += y;
        __syncthreads();
    }
    if (t < NSCB) bsum[t] = s[t] - v;  // exclusive
}

// phase 3: propagate block offsets
__global__ void k_scan3(int* __restrict__ off, const int* __restrict__ bsum) {
    int g = blockIdx.x * 1024 + threadIdx.x;
    if (g < NSEG) off[g] += bsum[blockIdx.x];
}

// ---------------- fill segment-sorted src list ----------------
__global__ void k_fill(const int* __restrict__ src, const int* __restrict__ dst,
                       const int* __restrict__ et, const int* __restrict__ off,
                       int* __restrict__ fill, int* __restrict__ esrc) {
    int e = blockIdx.x * 256 + threadIdx.x;
    if (e >= N_EDGES) return;
    int seg = dst[e] * R + et[e];
    int idx = off[seg] + atomicAdd(&fill[seg], 1);
    esrc[idx] = src[e];
}

// ---------------- BN column stats: gs[0..127]=sum, gs[128..255]=sumsq ----------------
__global__ void k_bnstats(const float* __restrict__ h, float* __restrict__ gs) {
    int c = threadIdx.x & 127;
    int rl = threadIdx.x >> 7;
    float s = 0.f, q = 0.f;
    for (int r = blockIdx.x * 2 + rl; r < N_NODES; r += gridDim.x * 2) {
        float v = h[(size_t)r * F + c];
        s += v; q += v * v;
    }
    __shared__ float ls[256], lq[256];
    ls[threadIdx.x] = s; lq[threadIdx.x] = q;
    __syncthreads();
    if (rl == 0) {
        atomicAdd(&gs[c], ls[c] + ls[c + 128]);
        atomicAdd(&gs[128 + c], lq[c] + lq[c + 128]);
    }
}

// ---------------- fused BN-apply + GEMM: [y|z] = bn(h) @ [Wr0|Wr1|Wroot] ----------------
// 64x64 tile, 4 waves, full K=128 staged. LDS pad: stride 136 bf16 (2-way = free).
__launch_bounds__(256)
__global__ void k_gemm(const float* __restrict__ h, const float* __restrict__ gs,
                       const bf16* __restrict__ Bt, const float* __restrict__ bias,
                       bf16* __restrict__ y, float* __restrict__ z) {
    __shared__ bf16 As[64 * 136];
    __shared__ bf16 Bs[64 * 136];
    __shared__ float mu_s[128], rs_s[128];
    int t = threadIdx.x;
    if (t < 128) {
        float m = gs[t] * (1.0f / N_NODES);
        float q = gs[128 + t] * (1.0f / N_NODES);
        mu_s[t] = m;
        rs_s[t] = rsqrtf(q - m * m + BN_EPS);
    }
    __syncthreads();
    int m0 = blockIdx.x * 64;
    int n0 = blockIdx.y * 64;
    // stage B tile (Bt rows are output-cols, contiguous K)
    {
        int n = t >> 2;
        int c0 = (t & 3) * 32;
        const bf16* sp = Bt + (size_t)(n0 + n) * F + c0;
        bf16* dp = Bs + n * 136 + c0;
        for (int i = 0; i < 4; i++)
            *(short8*)(dp + i * 8) = *(const short8*)(sp + i * 8);
    }
    // stage A tile with BN applied, f32 -> bf16
    for (int i = 0; i < 32; i++) {
        int idx = t + i * 256;
        int row = idx >> 7, col = idx & 127;
        int m = m0 + row;
        float v = (m < N_NODES) ? h[(size_t)m * F + col] : 0.0f;
        float hb = (v - mu_s[col]) * rs_s[col] + BETA;
        As[row * 136 + col] = __float2bfloat16(hb);
    }
    __syncthreads();
    int w = t >> 6;
    int lane = t & 63;
    int lm = lane & 15;   // A-row / B-col / D-col
    int lq = lane >> 4;   // quad -> k chunk / D-row group
    floatx4 acc[4];
    for (int j = 0; j < 4; j++) acc[j] = (floatx4){0.f, 0.f, 0.f, 0.f};
    for (int ki = 0; ki < 4; ki++) {
        int k = ki * 32 + lq * 8;
        short8 a = *(const short8*)(As + (w * 16 + lm) * 136 + k);
        for (int j = 0; j < 4; j++) {
            short8 b = *(const short8*)(Bs + (j * 16 + lm) * 136 + k);
            acc[j] = __builtin_amdgcn_mfma_f32_16x16x32_bf16(a, b, acc[j], 0, 0, 0);
        }
    }
    // epilogue: D[m][n], m=(lane>>4)*4+reg, n=lane&15 (verified m89 mapping)
    for (int j = 0; j < 4; j++) {
        for (int reg = 0; reg < 4; reg++) {
            int m = m0 + w * 16 + lq * 4 + reg;
            int n = n0 + j * 16 + lm;
            if (m < N_NODES) {
                float v = acc[j][reg];
                if (n < 256) y[(size_t)m * 256 + n] = __float2bfloat16(v);
                else z[(size_t)m * F + (n - 256)] = v + bias[n - 256];
            }
        }
    }
}

// ---------------- per-node pull aggregation + relu + residual ----------------
__global__ void k_aggregate(const bf16* __restrict__ y, const float* __restrict__ z,
                            const int* __restrict__ cnt, const int* __restrict__ off,
                            const int* __restrict__ esrc,
                            float* __restrict__ h, float* __restrict__ outp, int layer) {
    int wid = (blockIdx.x * 256 + threadIdx.x) >> 6;
    int lane = threadIdx.x & 63;
    if (wid >= N_NODES) return;
    int n = wid;
    int f = lane * 2;
    float2 zz = *(const float2*)(z + (size_t)n * F + f);
    float a0 = zz.x, a1 = zz.y;
    for (int r = 0; r < R; r++) {
        int seg = n * R + r;
        int c = cnt[seg];
        if (c > 0) {
            int o = off[seg];
            float s0 = 0.f, s1 = 0.f;
            for (int i = 0; i < c; i++) {
                int sn = esrc[o + i];
                __hip_bfloat162 vv = *(const __hip_bfloat162*)(y + (size_t)sn * 256 + r * F + f);
                s0 += __bfloat162float(vv.x);
                s1 += __bfloat162float(vv.y);
            }
            float inv = 1.0f / (float)c;
            a0 += s0 * inv; a1 += s1 * inv;
        }
    }
    a0 = fmaxf(a0, 0.f);
    a1 = fmaxf(a1, 0.f);
    if (layer > 0) {
        float2 hp = *(const float2*)(h + (size_t)n * F + f);
        a0 += hp.x; a1 += hp.y;
    }
    float2 o2; o2.x = a0; o2.y = a1;
    *(float2*)(h + (size_t)n * F + f) = o2;
    if (outp) {
        float2 q2; q2.x = a0; q2.y = a1;
        *(float2*)(outp + (size_t)n * F + f) = q2;
    }
}

extern "C" void kernel_launch(void* const* d_in, const int* in_sizes, int n_in,
                              void* d_out, int out_size, void* d_ws, size_t ws_size,
                              hipStream_t stream) {
    const float* x       = (const float*)d_in[0];
    const int*   eidx    = (const int*)d_in[1];
    const int*   etype   = (const int*)d_in[2];
    const float* W0_rel  = (const float*)d_in[3];
    const float* W0_root = (const float*)d_in[4];
    const float* b0      = (const float*)d_in[5];
    const float* Ws_rel  = (const float*)d_in[6];
    const float* Ws_root = (const float*)d_in[7];
    const float* bs      = (const float*)d_in[8];
    const int* src = eidx;
    const int* dst = eidx + N_EDGES;

    char* w = (char*)d_ws;
    float* h   = (float*)w; w += (size_t)N_NODES * F * 4;     // 25.6 MB
    float* z   = (float*)w; w += (size_t)N_NODES * F * 4;     // 25.6 MB
    bf16*  y   = (bf16*)w;  w += (size_t)N_NODES * 256 * 2;   // 25.6 MB
    bf16*  Bt  = (bf16*)w;  w += (size_t)NLAYER * NB * F * 2; // 384 KB
    int* cnt   = (int*)w;   w += (size_t)NSEG * 4;            // contiguous zero region:
    int* fill  = (int*)w;   w += (size_t)NSEG * 4;            //   cnt | fill | stats
    float* stats = (float*)w; w += (size_t)NLAYER * 256 * 4;
    int* off   = (int*)w;   w += (size_t)NSEG * 4;
    int* esrc  = (int*)w;   w += (size_t)N_EDGES * 4;
    int* bsum  = (int*)w;   w += 128 * 4;                     // total ~77 MB

    hipMemsetAsync(cnt, 0, (size_t)NSEG * 4 * 2 + (size_t)NLAYER * 256 * 4, stream);
    k_wt<<<(NLAYER * NB * F + 255) / 256, 256, 0, stream>>>(W0_rel, W0_root, Ws_rel, Ws_root, Bt);
    k_count<<<(N_EDGES + 255) / 256, 256, 0, stream>>>(dst, etype, cnt);
    k_scan1<<<NSCB, 1024, 0, stream>>>(cnt, off, bsum);
    k_scan2<<<1, 128, 0, stream>>>(bsum);
    k_scan3<<<NSCB, 1024, 0, stream>>>(off, bsum);
    k_fill<<<(N_EDGES + 255) / 256, 256, 0, stream>>>(src, dst, etype, off, fill, esrc);

    for (int l = 0; l < NLAYER; l++) {
        float* gs = stats + l * 256;
        const float* bias = (l == 0) ? b0 : (bs + (size_t)(l - 1) * F);
        const float* hin = (l == 0) ? x : h;
        k_bnstats<<<512, 256, 0, stream>>>(hin, gs);
        k_gemm<<<dim3((N_NODES + 63) / 64, NB / 64), 256, 0, stream>>>(
            hin, gs, Bt + (size_t)l * NB * F, bias, y, z);
        k_aggregate<<<(N_NODES * 64 + 255) / 256, 256, 0, stream>>>(
            y, z, cnt, off, esrc, h, (l == 3) ? (float*)d_out : nullptr, l);
    }
}

// Round 4
// 752.233 us; speedup vs baseline: 1.3348x; 1.0947x over previous
//
#include <hip/hip_runtime.h>
#include <hip/hip_bf16.h>

#define N_NODES 50000
#define N_EDGES 600000
#define F 128
#define R 2
#define NLAYER 4
#define NSEG (N_NODES * R)  /* 100000 */
#define NSCB 98             /* scan blocks: ceil(100000/1024) */
#define NB 384              /* gemm out cols: 256 y + 128 z */
#define BN_EPS 1e-5f
#define BETA 1e-4f

typedef __hip_bfloat16 bf16;
typedef __attribute__((ext_vector_type(8))) short short8;  // 8 bf16 (4 VGPRs)
typedef __attribute__((ext_vector_type(4))) float floatx4; // 4 fp32 acc

// ---------------- weight transpose + f32->bf16: Bt[l][j][d] = W[l][d][j] ----------------
// cols j: [0,128)=W_rel[0], [128,256)=W_rel[1], [256,384)=W_root
__global__ void k_wt(const float* __restrict__ W0_rel, const float* __restrict__ W0_root,
                     const float* __restrict__ Ws_rel, const float* __restrict__ Ws_root,
                     bf16* __restrict__ Bt) {
    int idx = blockIdx.x * 256 + threadIdx.x;
    if (idx >= NLAYER * NB * F) return;
    int l = idx / (NB * F);
    int rem = idx % (NB * F);
    int j = rem / F, d = rem % F;
    float v;
    if (j < 256) {
        int r = j >> 7, c = j & 127;
        v = (l == 0) ? W0_rel[(r * F + d) * F + c]
                     : Ws_rel[((size_t)((l - 1) * R + r) * F + d) * F + c];
    } else {
        int c = j - 256;
        v = (l == 0) ? W0_root[d * F + c]
                     : Ws_root[((size_t)(l - 1) * F + d) * F + c];
    }
    Bt[idx] = __float2bfloat16(v);
}

// ---------------- segment counts ----------------
__global__ void k_count(const int* __restrict__ dst, const int* __restrict__ et,
                        int* __restrict__ cnt) {
    int e = blockIdx.x * 256 + threadIdx.x;
    if (e < N_EDGES) atomicAdd(&cnt[dst[e] * R + et[e]], 1);
}

// ---------------- multi-block exclusive scan of cnt ----------------
__global__ void k_scan1(const int* __restrict__ cnt, int* __restrict__ off,
                        int* __restrict__ bsum) {
    int t = threadIdx.x;
    int g = blockIdx.x * 1024 + t;
    int v = (g < NSEG) ? cnt[g] : 0;
    int lane = t & 63;
    int wv = t >> 6;
    int x = v;
    for (int d = 1; d < 64; d <<= 1) {
        int y = __shfl_up(x, d, 64);
        if (lane >= d) x += y;
    }
    __shared__ int wtot[16];
    if (lane == 63) wtot[wv] = x;
    __syncthreads();
    if (t < 16) {
        int s = wtot[t];
        for (int d = 1; d < 16; d <<= 1) {
            int y = __shfl_up(s, d, 64);
            if (t >= d) s += y;
        }
        wtot[t] = s;
    }
    __syncthreads();
    int wpre = (wv == 0) ? 0 : wtot[wv - 1];
    int incl = x + wpre;
    if (g < NSEG) off[g] = incl - v;  // exclusive within block
    if (t == 1023) bsum[blockIdx.x] = incl;
}

__global__ void k_scan2(int* __restrict__ bsum) {
    __shared__ int s[128];
    int t = threadIdx.x;
    int v = (t < NSCB) ? bsum[t] : 0;
    s[t] = v;
    __syncthreads();
    for (int d = 1; d < 128; d <<= 1) {
        int y = (t >= d) ? s[t - d] : 0;
        __syncthreads();
        s[t] += y;
        __syncthreads();
    }
    if (t < NSCB) bsum[t] = s[t] - v;  // exclusive
}

__global__ void k_scan3(int* __restrict__ off, const int* __restrict__ bsum) {
    int g = blockIdx.x * 1024 + threadIdx.x;
    if (g < NSEG) off[g] += bsum[blockIdx.x];
}

// ---------------- fill segment-sorted src list ----------------
__global__ void k_fill(const int* __restrict__ src, const int* __restrict__ dst,
                       const int* __restrict__ et, const int* __restrict__ off,
                       int* __restrict__ fill, int* __restrict__ esrc) {
    int e = blockIdx.x * 256 + threadIdx.x;
    if (e >= N_EDGES) return;
    int seg = dst[e] * R + et[e];
    int idx = off[seg] + atomicAdd(&fill[seg], 1);
    esrc[idx] = src[e];
}

// ---------------- BN column stats: gs[0..127]=sum, gs[128..255]=sumsq ----------------
__global__ void k_bnstats(const float* __restrict__ h, float* __restrict__ gs) {
    int c = threadIdx.x & 127;
    int rl = threadIdx.x >> 7;
    float s = 0.f, q = 0.f;
    for (int r = blockIdx.x * 2 + rl; r < N_NODES; r += gridDim.x * 2) {
        float v = h[(size_t)r * F + c];
        s += v; q += v * v;
    }
    __shared__ float ls[256], lq[256];
    ls[threadIdx.x] = s; lq[threadIdx.x] = q;
    __syncthreads();
    if (rl == 0) {
        atomicAdd(&gs[c], ls[c] + ls[c + 128]);
        atomicAdd(&gs[128 + c], lq[c] + lq[c + 128]);
    }
}

// ---------------- fused BN-apply + GEMM: [y|z] = bn(h) @ [Wr0|Wr1|Wroot] ----------------
// One block = 64-row strip x all 384 cols. A staged once (float4 loads);
// B read directly from global (96 KB total, L1/L2-hot). 96 MFMAs/wave.
__launch_bounds__(256)
__global__ void k_gemm(const float* __restrict__ h, const float* __restrict__ gs,
                       const bf16* __restrict__ Bt, const float* __restrict__ bias,
                       bf16* __restrict__ y, float* __restrict__ z) {
    __shared__ bf16 As[64 * 136];
    int t = threadIdx.x;
    int m0 = blockIdx.x * 64;
    // per-thread BN constants for its 4 fixed columns
    int c4 = (t & 31) * 4;
    float mu[4], rs[4];
    for (int c = 0; c < 4; c++) {
        float mm = gs[c4 + c] * (1.0f / N_NODES);
        float qq = gs[128 + c4 + c] * (1.0f / N_NODES);
        mu[c] = mm;
        rs[c] = rsqrtf(qq - mm * mm + BN_EPS);
    }
    int r0 = t >> 5;
    for (int it = 0; it < 8; it++) {
        int row = r0 + it * 8;
        int m = m0 + row;
        float4 v = {0.f, 0.f, 0.f, 0.f};
        if (m < N_NODES) v = *(const float4*)(h + (size_t)m * F + c4);
        bf16 o[4];
        o[0] = __float2bfloat16((v.x - mu[0]) * rs[0] + BETA);
        o[1] = __float2bfloat16((v.y - mu[1]) * rs[1] + BETA);
        o[2] = __float2bfloat16((v.z - mu[2]) * rs[2] + BETA);
        o[3] = __float2bfloat16((v.w - mu[3]) * rs[3] + BETA);
        *(double*)(As + row * 136 + c4) = *(const double*)o;
    }
    __syncthreads();
    int w = t >> 6;
    int lane = t & 63;
    int lm = lane & 15;   // A-row / B-col / D-col
    int lq = lane >> 4;   // quad -> k chunk / D-row group
    short8 a[4];
    for (int ki = 0; ki < 4; ki++)
        a[ki] = *(const short8*)(As + (w * 16 + lm) * 136 + ki * 32 + lq * 8);
    const bf16* bp = Bt + (size_t)lm * F + lq * 8;
    for (int jp = 0; jp < 12; jp++) {
        int j0 = jp * 2, j1 = j0 + 1;
        short8 b0[4], b1[4];
        for (int ki = 0; ki < 4; ki++) {
            b0[ki] = *(const short8*)(bp + (size_t)j0 * 16 * F + ki * 32);
            b1[ki] = *(const short8*)(bp + (size_t)j1 * 16 * F + ki * 32);
        }
        floatx4 acc0 = {0.f, 0.f, 0.f, 0.f}, acc1 = {0.f, 0.f, 0.f, 0.f};
        for (int ki = 0; ki < 4; ki++)
            acc0 = __builtin_amdgcn_mfma_f32_16x16x32_bf16(a[ki], b0[ki], acc0, 0, 0, 0);
        for (int ki = 0; ki < 4; ki++)
            acc1 = __builtin_amdgcn_mfma_f32_16x16x32_bf16(a[ki], b1[ki], acc1, 0, 0, 0);
        int mb = m0 + w * 16 + lq * 4;
        for (int pair = 0; pair < 2; pair++) {
            floatx4 ac = pair ? acc1 : acc0;
            int j = pair ? j1 : j0;
            int n = j * 16 + lm;
            if (n < 256) {
                for (int reg = 0; reg < 4; reg++) {
                    int m = mb + reg;
                    if (m < N_NODES)
                        y[(size_t)m * 256 + n] = __float2bfloat16(ac[reg]);
                }
            } else {
                float bv = bias[n - 256];
                for (int reg = 0; reg < 4; reg++) {
                    int m = mb + reg;
                    if (m < N_NODES)
                        z[(size_t)m * F + (n - 256)] = ac[reg] + bv;
                }
            }
        }
    }
}

// ---------------- per-node pull aggregation + relu + residual ----------------
__global__ void k_aggregate(const bf16* __restrict__ y, const float* __restrict__ z,
                            const int* __restrict__ cnt, const int* __restrict__ off,
                            const int* __restrict__ esrc,
                            float* __restrict__ h, float* __restrict__ outp, int layer) {
    int wid = (blockIdx.x * 256 + threadIdx.x) >> 6;
    int lane = threadIdx.x & 63;
    if (wid >= N_NODES) return;
    int n = wid;
    int f = lane * 2;
    float2 zz = *(const float2*)(z + (size_t)n * F + f);
    float a0 = zz.x, a1 = zz.y;
    for (int r = 0; r < R; r++) {
        int seg = n * R + r;
        int c = cnt[seg];
        if (c > 0) {
            int o = off[seg];
            float s0 = 0.f, s1 = 0.f;
            for (int i = 0; i < c; i++) {
                int sn = esrc[o + i];
                __hip_bfloat162 vv = *(const __hip_bfloat162*)(y + (size_t)sn * 256 + r * F + f);
                s0 += __bfloat162float(vv.x);
                s1 += __bfloat162float(vv.y);
            }
            float inv = 1.0f / (float)c;
            a0 += s0 * inv; a1 += s1 * inv;
        }
    }
    a0 = fmaxf(a0, 0.f);
    a1 = fmaxf(a1, 0.f);
    if (layer > 0) {
        float2 hp = *(const float2*)(h + (size_t)n * F + f);
        a0 += hp.x; a1 += hp.y;
    }
    float2 o2; o2.x = a0; o2.y = a1;
    *(float2*)(h + (size_t)n * F + f) = o2;
    if (outp) {
        float2 q2; q2.x = a0; q2.y = a1;
        *(float2*)(outp + (size_t)n * F + f) = q2;
    }
}

extern "C" void kernel_launch(void* const* d_in, const int* in_sizes, int n_in,
                              void* d_out, int out_size, void* d_ws, size_t ws_size,
                              hipStream_t stream) {
    const float* x       = (const float*)d_in[0];
    const int*   eidx    = (const int*)d_in[1];
    const int*   etype   = (const int*)d_in[2];
    const float* W0_rel  = (const float*)d_in[3];
    const float* W0_root = (const float*)d_in[4];
    const float* b0      = (const float*)d_in[5];
    const float* Ws_rel  = (const float*)d_in[6];
    const float* Ws_root = (const float*)d_in[7];
    const float* bs      = (const float*)d_in[8];
    const int* src = eidx;
    const int* dst = eidx + N_EDGES;

    char* w = (char*)d_ws;
    float* h   = (float*)w; w += (size_t)N_NODES * F * 4;     // 25.6 MB
    float* z   = (float*)w; w += (size_t)N_NODES * F * 4;     // 25.6 MB
    bf16*  y   = (bf16*)w;  w += (size_t)N_NODES * 256 * 2;   // 25.6 MB
    bf16*  Bt  = (bf16*)w;  w += (size_t)NLAYER * NB * F * 2; // 384 KB
    int* cnt   = (int*)w;   w += (size_t)NSEG * 4;            // contiguous zero region:
    int* fill  = (int*)w;   w += (size_t)NSEG * 4;            //   cnt | fill | stats
    float* stats = (float*)w; w += (size_t)NLAYER * 256 * 4;
    int* off   = (int*)w;   w += (size_t)NSEG * 4;
    int* esrc  = (int*)w;   w += (size_t)N_EDGES * 4;
    int* bsum  = (int*)w;   w += 128 * 4;                     // total ~77 MB

    hipMemsetAsync(cnt, 0, (size_t)NSEG * 4 * 2 + (size_t)NLAYER * 256 * 4, stream);
    k_wt<<<(NLAYER * NB * F + 255) / 256, 256, 0, stream>>>(W0_rel, W0_root, Ws_rel, Ws_root, Bt);
    k_count<<<(N_EDGES + 255) / 256, 256, 0, stream>>>(dst, etype, cnt);
    k_scan1<<<NSCB, 1024, 0, stream>>>(cnt, off, bsum);
    k_scan2<<<1, 128, 0, stream>>>(bsum);
    k_scan3<<<NSCB, 1024, 0, stream>>>(off, bsum);
    k_fill<<<(N_EDGES + 255) / 256, 256, 0, stream>>>(src, dst, etype, off, fill, esrc);

    for (int l = 0; l < NLAYER; l++) {
        float* gs = stats + l * 256;
        const float* bias = (l == 0) ? b0 : (bs + (size_t)(l - 1) * F);
        const float* hin = (l == 0) ? x : h;
        k_bnstats<<<512, 256, 0, stream>>>(hin, gs);
        k_gemm<<<(N_NODES + 63) / 64, 256, 0, stream>>>(
            hin, gs, Bt + (size_t)l * NB * F, bias, y, z);
        k_aggregate<<<(N_NODES * 64 + 255) / 256, 256, 0, stream>>>(
            y, z, cnt, off, esrc, h, (l == 3) ? (float*)d_out : nullptr, l);
    }
}

// Round 5
// 626.238 us; speedup vs baseline: 1.6034x; 1.2012x over previous
//
#include <hip/hip_runtime.h>
#include <hip/hip_bf16.h>

#define N_NODES 50000
#define N_EDGES 600000
#define F 128
#define R 2
#define NLAYER 4
#define NSEG (N_NODES * R)  /* 100000 */
#define NSCB 98             /* scan blocks: ceil(100000/1024) */
#define NB 384              /* gemm out cols: 256 y + 128 z */
#define BN_EPS 1e-5f
#define BETA 1e-4f

typedef __hip_bfloat16 bf16;
typedef __attribute__((ext_vector_type(8))) short short8;  // 8 bf16 (4 VGPRs)
typedef __attribute__((ext_vector_type(4))) float floatx4; // 4 fp32 acc

// ---------------- weight transpose + f32->bf16: Bt[l][j][d] = W[l][d][j] ----------------
// cols j: [0,128)=W_rel[0], [128,256)=W_rel[1], [256,384)=W_root
__global__ void k_wt(const float* __restrict__ W0_rel, const float* __restrict__ W0_root,
                     const float* __restrict__ Ws_rel, const float* __restrict__ Ws_root,
                     bf16* __restrict__ Bt) {
    int idx = blockIdx.x * 256 + threadIdx.x;
    if (idx >= NLAYER * NB * F) return;
    int l = idx / (NB * F);
    int rem = idx % (NB * F);
    int j = rem / F, d = rem % F;
    float v;
    if (j < 256) {
        int r = j >> 7, c = j & 127;
        v = (l == 0) ? W0_rel[(r * F + d) * F + c]
                     : Ws_rel[((size_t)((l - 1) * R + r) * F + d) * F + c];
    } else {
        int c = j - 256;
        v = (l == 0) ? W0_root[d * F + c]
                     : Ws_root[((size_t)(l - 1) * F + d) * F + c];
    }
    Bt[idx] = __float2bfloat16(v);
}

// ---------------- segment counts ----------------
__global__ void k_count(const int* __restrict__ dst, const int* __restrict__ et,
                        int* __restrict__ cnt) {
    int e = blockIdx.x * 256 + threadIdx.x;
    if (e < N_EDGES) atomicAdd(&cnt[dst[e] * R + et[e]], 1);
}

// ---------------- multi-block exclusive scan of cnt ----------------
__global__ void k_scan1(const int* __restrict__ cnt, int* __restrict__ off,
                        int* __restrict__ bsum) {
    int t = threadIdx.x;
    int g = blockIdx.x * 1024 + t;
    int v = (g < NSEG) ? cnt[g] : 0;
    int lane = t & 63;
    int wv = t >> 6;
    int x = v;
    for (int d = 1; d < 64; d <<= 1) {
        int y = __shfl_up(x, d, 64);
        if (lane >= d) x += y;
    }
    __shared__ int wtot[16];
    if (lane == 63) wtot[wv] = x;
    __syncthreads();
    if (t < 16) {
        int s = wtot[t];
        for (int d = 1; d < 16; d <<= 1) {
            int y = __shfl_up(s, d, 64);
            if (t >= d) s += y;
        }
        wtot[t] = s;
    }
    __syncthreads();
    int wpre = (wv == 0) ? 0 : wtot[wv - 1];
    int incl = x + wpre;
    if (g < NSEG) off[g] = incl - v;  // exclusive within block
    if (t == 1023) bsum[blockIdx.x] = incl;
}

__global__ void k_scan2(int* __restrict__ bsum) {
    __shared__ int s[128];
    int t = threadIdx.x;
    int v = (t < NSCB) ? bsum[t] : 0;
    s[t] = v;
    __syncthreads();
    for (int d = 1; d < 128; d <<= 1) {
        int y = (t >= d) ? s[t - d] : 0;
        __syncthreads();
        s[t] += y;
        __syncthreads();
    }
    if (t < NSCB) bsum[t] = s[t] - v;  // exclusive
}

__global__ void k_scan3(int* __restrict__ off, const int* __restrict__ bsum) {
    int g = blockIdx.x * 1024 + threadIdx.x;
    if (g < NSEG) off[g] += bsum[blockIdx.x];
}

// ---------------- fill segment-sorted src list ----------------
__global__ void k_fill(const int* __restrict__ src, const int* __restrict__ dst,
                       const int* __restrict__ et, const int* __restrict__ off,
                       int* __restrict__ fill, int* __restrict__ esrc) {
    int e = blockIdx.x * 256 + threadIdx.x;
    if (e >= N_EDGES) return;
    int seg = dst[e] * R + et[e];
    int idx = off[seg] + atomicAdd(&fill[seg], 1);
    esrc[idx] = src[e];
}

// ---------------- BN column stats: gs[0..127]=sum, gs[128..255]=sumsq ----------------
__global__ void k_bnstats(const float* __restrict__ h, float* __restrict__ gs) {
    int c = threadIdx.x & 127;
    int rl = threadIdx.x >> 7;
    float s = 0.f, q = 0.f;
    for (int r = blockIdx.x * 2 + rl; r < N_NODES; r += gridDim.x * 2) {
        float v = h[(size_t)r * F + c];
        s += v; q += v * v;
    }
    __shared__ float ls[256], lq[256];
    ls[threadIdx.x] = s; lq[threadIdx.x] = q;
    __syncthreads();
    if (rl == 0) {
        atomicAdd(&gs[c], ls[c] + ls[c + 128]);
        atomicAdd(&gs[128 + c], lq[c] + lq[c + 128]);
    }
}

// ---------------- fused BN-apply + GEMM: [y|z] = bn(h) @ [Wr0|Wr1|Wroot] ----------------
// One block = 64-row strip x all 384 cols. A staged once (float4 loads);
// B read directly from global (96 KB total, L1/L2-hot). 96 MFMAs/wave.
__launch_bounds__(256)
__global__ void k_gemm(const float* __restrict__ h, const float* __restrict__ gs,
                       const bf16* __restrict__ Bt, const float* __restrict__ bias,
                       bf16* __restrict__ y, float* __restrict__ z) {
    __shared__ bf16 As[64 * 136];
    int t = threadIdx.x;
    int m0 = blockIdx.x * 64;
    // per-thread BN constants for its 4 fixed columns
    int c4 = (t & 31) * 4;
    float mu[4], rs[4];
    for (int c = 0; c < 4; c++) {
        float mm = gs[c4 + c] * (1.0f / N_NODES);
        float qq = gs[128 + c4 + c] * (1.0f / N_NODES);
        mu[c] = mm;
        rs[c] = rsqrtf(qq - mm * mm + BN_EPS);
    }
    int r0 = t >> 5;
    for (int it = 0; it < 8; it++) {
        int row = r0 + it * 8;
        int m = m0 + row;
        float4 v = {0.f, 0.f, 0.f, 0.f};
        if (m < N_NODES) v = *(const float4*)(h + (size_t)m * F + c4);
        bf16 o[4];
        o[0] = __float2bfloat16((v.x - mu[0]) * rs[0] + BETA);
        o[1] = __float2bfloat16((v.y - mu[1]) * rs[1] + BETA);
        o[2] = __float2bfloat16((v.z - mu[2]) * rs[2] + BETA);
        o[3] = __float2bfloat16((v.w - mu[3]) * rs[3] + BETA);
        *(double*)(As + row * 136 + c4) = *(const double*)o;
    }
    __syncthreads();
    int w = t >> 6;
    int lane = t & 63;
    int lm = lane & 15;   // A-row / B-col / D-col
    int lq = lane >> 4;   // quad -> k chunk / D-row group
    short8 a[4];
    for (int ki = 0; ki < 4; ki++)
        a[ki] = *(const short8*)(As + (w * 16 + lm) * 136 + ki * 32 + lq * 8);
    const bf16* bp = Bt + (size_t)lm * F + lq * 8;
    for (int jp = 0; jp < 12; jp++) {
        int j0 = jp * 2, j1 = j0 + 1;
        short8 b0[4], b1[4];
        for (int ki = 0; ki < 4; ki++) {
            b0[ki] = *(const short8*)(bp + (size_t)j0 * 16 * F + ki * 32);
            b1[ki] = *(const short8*)(bp + (size_t)j1 * 16 * F + ki * 32);
        }
        floatx4 acc0 = {0.f, 0.f, 0.f, 0.f}, acc1 = {0.f, 0.f, 0.f, 0.f};
        for (int ki = 0; ki < 4; ki++)
            acc0 = __builtin_amdgcn_mfma_f32_16x16x32_bf16(a[ki], b0[ki], acc0, 0, 0, 0);
        for (int ki = 0; ki < 4; ki++)
            acc1 = __builtin_amdgcn_mfma_f32_16x16x32_bf16(a[ki], b1[ki], acc1, 0, 0, 0);
        int mb = m0 + w * 16 + lq * 4;
        for (int pair = 0; pair < 2; pair++) {
            floatx4 ac = pair ? acc1 : acc0;
            int j = pair ? j1 : j0;
            int n = j * 16 + lm;
            if (n < 256) {
                for (int reg = 0; reg < 4; reg++) {
                    int m = mb + reg;
                    if (m < N_NODES)
                        y[(size_t)m * 256 + n] = __float2bfloat16(ac[reg]);
                }
            } else {
                float bv = bias[n - 256];
                for (int reg = 0; reg < 4; reg++) {
                    int m = mb + reg;
                    if (m < N_NODES)
                        z[(size_t)m * F + (n - 256)] = ac[reg] + bv;
                }
            }
        }
    }
}

// ---------------- per-node pull aggregation + relu + residual ----------------
// Fused over both relation segments (contiguous in esrc); mean folded into
// fma weight. Unroll-4 with independent accumulators for memory-level par.
__global__ void k_aggregate(const bf16* __restrict__ y, const float* __restrict__ z,
                            const int* __restrict__ cnt, const int* __restrict__ off,
                            const int* __restrict__ esrc,
                            float* __restrict__ h, float* __restrict__ outp, int layer) {
    int wid = (blockIdx.x * 256 + threadIdx.x) >> 6;
    int lane = threadIdx.x & 63;
    if (wid >= N_NODES) return;
    int n = wid;
    int f = lane * 2;
    int2 cc = *(const int2*)(cnt + n * R);
    int c0 = cc.x, c1 = cc.y;
    int o0 = off[n * R];
    int ctot = c0 + c1;
    float inv0 = (c0 > 0) ? 1.0f / (float)c0 : 0.f;
    float inv1 = (c1 > 0) ? 1.0f / (float)c1 : 0.f;
    const bf16* yb = y + f;
    float s0 = 0.f, s1 = 0.f, t0 = 0.f, t1 = 0.f;
    float u0 = 0.f, u1 = 0.f, v0 = 0.f, v1 = 0.f;
    int i = 0;
    for (; i + 4 <= ctot; i += 4) {
        int sn0 = esrc[o0 + i];
        int sn1 = esrc[o0 + i + 1];
        int sn2 = esrc[o0 + i + 2];
        int sn3 = esrc[o0 + i + 3];
        int ro0 = (i     >= c0) ? 128 : 0; float w0 = (i     >= c0) ? inv1 : inv0;
        int ro1 = (i + 1 >= c0) ? 128 : 0; float w1 = (i + 1 >= c0) ? inv1 : inv0;
        int ro2 = (i + 2 >= c0) ? 128 : 0; float w2 = (i + 2 >= c0) ? inv1 : inv0;
        int ro3 = (i + 3 >= c0) ? 128 : 0; float w3 = (i + 3 >= c0) ? inv1 : inv0;
        __hip_bfloat162 p0 = *(const __hip_bfloat162*)(yb + (size_t)sn0 * 256 + ro0);
        __hip_bfloat162 p1 = *(const __hip_bfloat162*)(yb + (size_t)sn1 * 256 + ro1);
        __hip_bfloat162 p2 = *(const __hip_bfloat162*)(yb + (size_t)sn2 * 256 + ro2);
        __hip_bfloat162 p3 = *(const __hip_bfloat162*)(yb + (size_t)sn3 * 256 + ro3);
        s0 = fmaf(__bfloat162float(p0.x), w0, s0);
        s1 = fmaf(__bfloat162float(p0.y), w0, s1);
        t0 = fmaf(__bfloat162float(p1.x), w1, t0);
        t1 = fmaf(__bfloat162float(p1.y), w1, t1);
        u0 = fmaf(__bfloat162float(p2.x), w2, u0);
        u1 = fmaf(__bfloat162float(p2.y), w2, u1);
        v0 = fmaf(__bfloat162float(p3.x), w3, v0);
        v1 = fmaf(__bfloat162float(p3.y), w3, v1);
    }
    for (; i < ctot; i++) {
        int sn = esrc[o0 + i];
        int ro = (i >= c0) ? 128 : 0;
        float ww = (i >= c0) ? inv1 : inv0;
        __hip_bfloat162 p = *(const __hip_bfloat162*)(yb + (size_t)sn * 256 + ro);
        s0 = fmaf(__bfloat162float(p.x), ww, s0);
        s1 = fmaf(__bfloat162float(p.y), ww, s1);
    }
    float2 zz = *(const float2*)(z + (size_t)n * F + f);
    float a0 = zz.x + ((s0 + t0) + (u0 + v0));
    float a1 = zz.y + ((s1 + t1) + (u1 + v1));
    a0 = fmaxf(a0, 0.f);
    a1 = fmaxf(a1, 0.f);
    if (layer > 0) {
        float2 hp = *(const float2*)(h + (size_t)n * F + f);
        a0 += hp.x; a1 += hp.y;
    }
    float2 o2; o2.x = a0; o2.y = a1;
    *(float2*)(h + (size_t)n * F + f) = o2;
    if (outp) {
        float2 q2; q2.x = a0; q2.y = a1;
        *(float2*)(outp + (size_t)n * F + f) = q2;
    }
}

extern "C" void kernel_launch(void* const* d_in, const int* in_sizes, int n_in,
                              void* d_out, int out_size, void* d_ws, size_t ws_size,
                              hipStream_t stream) {
    const float* x       = (const float*)d_in[0];
    const int*   eidx    = (const int*)d_in[1];
    const int*   etype   = (const int*)d_in[2];
    const float* W0_rel  = (const float*)d_in[3];
    const float* W0_root = (const float*)d_in[4];
    const float* b0      = (const float*)d_in[5];
    const float* Ws_rel  = (const float*)d_in[6];
    const float* Ws_root = (const float*)d_in[7];
    const float* bs      = (const float*)d_in[8];
    const int* src = eidx;
    const int* dst = eidx + N_EDGES;

    char* w = (char*)d_ws;
    float* h   = (float*)w; w += (size_t)N_NODES * F * 4;     // 25.6 MB
    float* z   = (float*)w; w += (size_t)N_NODES * F * 4;     // 25.6 MB
    bf16*  y   = (bf16*)w;  w += (size_t)N_NODES * 256 * 2;   // 25.6 MB
    bf16*  Bt  = (bf16*)w;  w += (size_t)NLAYER * NB * F * 2; // 384 KB
    int* cnt   = (int*)w;   w += (size_t)NSEG * 4;            // contiguous zero region:
    int* fill  = (int*)w;   w += (size_t)NSEG * 4;            //   cnt | fill | stats
    float* stats = (float*)w; w += (size_t)NLAYER * 256 * 4;
    int* off   = (int*)w;   w += (size_t)NSEG * 4;
    int* esrc  = (int*)w;   w += (size_t)N_EDGES * 4;
    int* bsum  = (int*)w;   w += 128 * 4;                     // total ~77 MB

    hipMemsetAsync(cnt, 0, (size_t)NSEG * 4 * 2 + (size_t)NLAYER * 256 * 4, stream);
    k_wt<<<(NLAYER * NB * F + 255) / 256, 256, 0, stream>>>(W0_rel, W0_root, Ws_rel, Ws_root, Bt);
    k_count<<<(N_EDGES + 255) / 256, 256, 0, stream>>>(dst, etype, cnt);
    k_scan1<<<NSCB, 1024, 0, stream>>>(cnt, off, bsum);
    k_scan2<<<1, 128, 0, stream>>>(bsum);
    k_scan3<<<NSCB, 1024, 0, stream>>>(off, bsum);
    k_fill<<<(N_EDGES + 255) / 256, 256, 0, stream>>>(src, dst, etype, off, fill, esrc);

    for (int l = 0; l < NLAYER; l++) {
        float* gs = stats + l * 256;
        const float* bias = (l == 0) ? b0 : (bs + (size_t)(l - 1) * F);
        const float* hin = (l == 0) ? x : h;
        k_bnstats<<<512, 256, 0, stream>>>(hin, gs);
        k_gemm<<<(N_NODES + 63) / 64, 256, 0, stream>>>(
            hin, gs, Bt + (size_t)l * NB * F, bias, y, z);
        k_aggregate<<<(N_NODES * 64 + 255) / 256, 256, 0, stream>>>(
            y, z, cnt, off, esrc, h, (l == 3) ? (float*)d_out : nullptr, l);
    }
}

// Round 6
// 624.050 us; speedup vs baseline: 1.6090x; 1.0035x over previous
//
#include <hip/hip_runtime.h>
#include <hip/hip_bf16.h>

#define N_NODES 50000
#define N_EDGES 600000
#define F 128
#define R 2
#define NLAYER 4
#define NSEG (N_NODES * R)  /* 100000 */
#define NSCB 98             /* scan blocks: ceil(100000/1024) */
#define NB 384              /* gemm out cols: 256 y + 128 z */
#define BN_EPS 1e-5f
#define BETA 1e-4f

typedef __hip_bfloat16 bf16;
typedef __attribute__((ext_vector_type(8))) short short8;  // 8 bf16 (4 VGPRs)
typedef __attribute__((ext_vector_type(4))) float floatx4; // 4 fp32 acc

// ---------------- weight transpose + f32->bf16: Bt[l][j][d] = W[l][d][j] ----------------
// cols j: [0,128)=W_rel[0], [128,256)=W_rel[1], [256,384)=W_root
__global__ void k_wt(const float* __restrict__ W0_rel, const float* __restrict__ W0_root,
                     const float* __restrict__ Ws_rel, const float* __restrict__ Ws_root,
                     bf16* __restrict__ Bt) {
    int idx = blockIdx.x * 256 + threadIdx.x;
    if (idx >= NLAYER * NB * F) return;
    int l = idx / (NB * F);
    int rem = idx % (NB * F);
    int j = rem / F, d = rem % F;
    float v;
    if (j < 256) {
        int r = j >> 7, c = j & 127;
        v = (l == 0) ? W0_rel[(r * F + d) * F + c]
                     : Ws_rel[((size_t)((l - 1) * R + r) * F + d) * F + c];
    } else {
        int c = j - 256;
        v = (l == 0) ? W0_root[d * F + c]
                     : Ws_root[((size_t)(l - 1) * F + d) * F + c];
    }
    Bt[idx] = __float2bfloat16(v);
}

// ---------------- segment counts ----------------
__global__ void k_count(const int* __restrict__ dst, const int* __restrict__ et,
                        int* __restrict__ cnt) {
    int e = blockIdx.x * 256 + threadIdx.x;
    if (e < N_EDGES) atomicAdd(&cnt[dst[e] * R + et[e]], 1);
}

// ---------------- multi-block exclusive scan of cnt ----------------
__global__ void k_scan1(const int* __restrict__ cnt, int* __restrict__ off,
                        int* __restrict__ bsum) {
    int t = threadIdx.x;
    int g = blockIdx.x * 1024 + t;
    int v = (g < NSEG) ? cnt[g] : 0;
    int lane = t & 63;
    int wv = t >> 6;
    int x = v;
    for (int d = 1; d < 64; d <<= 1) {
        int y = __shfl_up(x, d, 64);
        if (lane >= d) x += y;
    }
    __shared__ int wtot[16];
    if (lane == 63) wtot[wv] = x;
    __syncthreads();
    if (t < 16) {
        int s = wtot[t];
        for (int d = 1; d < 16; d <<= 1) {
            int y = __shfl_up(s, d, 64);
            if (t >= d) s += y;
        }
        wtot[t] = s;
    }
    __syncthreads();
    int wpre = (wv == 0) ? 0 : wtot[wv - 1];
    int incl = x + wpre;
    if (g < NSEG) off[g] = incl - v;  // exclusive within block
    if (t == 1023) bsum[blockIdx.x] = incl;
}

__global__ void k_scan2(int* __restrict__ bsum) {
    __shared__ int s[128];
    int t = threadIdx.x;
    int v = (t < NSCB) ? bsum[t] : 0;
    s[t] = v;
    __syncthreads();
    for (int d = 1; d < 128; d <<= 1) {
        int y = (t >= d) ? s[t - d] : 0;
        __syncthreads();
        s[t] += y;
        __syncthreads();
    }
    if (t < NSCB) bsum[t] = s[t] - v;  // exclusive
}

__global__ void k_scan3(int* __restrict__ off, const int* __restrict__ bsum) {
    int g = blockIdx.x * 1024 + threadIdx.x;
    if (g < NSEG) off[g] += bsum[blockIdx.x];
}

// ---------------- fill segment-sorted src list ----------------
__global__ void k_fill(const int* __restrict__ src, const int* __restrict__ dst,
                       const int* __restrict__ et, const int* __restrict__ off,
                       int* __restrict__ fill, int* __restrict__ esrc) {
    int e = blockIdx.x * 256 + threadIdx.x;
    if (e >= N_EDGES) return;
    int seg = dst[e] * R + et[e];
    int idx = off[seg] + atomicAdd(&fill[seg], 1);
    esrc[idx] = src[e];
}

// ---------------- BN column stats: gs[0..127]=sum, gs[128..255]=sumsq ----------------
__global__ void k_bnstats(const float* __restrict__ h, float* __restrict__ gs) {
    int c = threadIdx.x & 127;
    int rl = threadIdx.x >> 7;
    float s = 0.f, q = 0.f;
    for (int r = blockIdx.x * 2 + rl; r < N_NODES; r += gridDim.x * 2) {
        float v = h[(size_t)r * F + c];
        s += v; q += v * v;
    }
    __shared__ float ls[256], lq[256];
    ls[threadIdx.x] = s; lq[threadIdx.x] = q;
    __syncthreads();
    if (rl == 0) {
        atomicAdd(&gs[c], ls[c] + ls[c + 128]);
        atomicAdd(&gs[128 + c], lq[c] + lq[c + 128]);
    }
}

// ---------------- fused BN-apply + GEMM: [y|z] = bn(h) @ [Wr0|Wr1|Wroot] ----------------
// One block = 64-row strip x all 384 cols, 512 threads (8 waves).
// Wave w: m-subtile (w&3), n-half (w>>2). A staged once; B L2-hot global.
__launch_bounds__(512)
__global__ void k_gemm(const float* __restrict__ h, const float* __restrict__ gs,
                       const bf16* __restrict__ Bt, const float* __restrict__ bias,
                       bf16* __restrict__ y, float* __restrict__ z) {
    __shared__ bf16 As[64 * 136];
    int t = threadIdx.x;
    int m0 = blockIdx.x * 64;
    // per-thread BN constants for its 4 fixed columns
    int c4 = (t & 31) * 4;
    float mu[4], rs[4];
    for (int c = 0; c < 4; c++) {
        float mm = gs[c4 + c] * (1.0f / N_NODES);
        float qq = gs[128 + c4 + c] * (1.0f / N_NODES);
        mu[c] = mm;
        rs[c] = rsqrtf(qq - mm * mm + BN_EPS);
    }
    int r0 = t >> 5;  // 0..15
    for (int it = 0; it < 4; it++) {
        int row = r0 + it * 16;
        int m = m0 + row;
        float4 v = {0.f, 0.f, 0.f, 0.f};
        if (m < N_NODES) v = *(const float4*)(h + (size_t)m * F + c4);
        bf16 o[4];
        o[0] = __float2bfloat16((v.x - mu[0]) * rs[0] + BETA);
        o[1] = __float2bfloat16((v.y - mu[1]) * rs[1] + BETA);
        o[2] = __float2bfloat16((v.z - mu[2]) * rs[2] + BETA);
        o[3] = __float2bfloat16((v.w - mu[3]) * rs[3] + BETA);
        *(double*)(As + row * 136 + c4) = *(const double*)o;
    }
    __syncthreads();
    int w = t >> 6;
    int lane = t & 63;
    int msub = w & 3;
    int nh = w >> 2;
    int lm = lane & 15;   // A-row / B-col / D-col
    int lq = lane >> 4;   // quad -> k chunk / D-row group
    short8 a[4];
    for (int ki = 0; ki < 4; ki++)
        a[ki] = *(const short8*)(As + (msub * 16 + lm) * 136 + ki * 32 + lq * 8);
    const bf16* bp = Bt + (size_t)lm * F + lq * 8;
    for (int jp = nh * 6; jp < nh * 6 + 6; jp++) {
        int j0 = jp * 2, j1 = j0 + 1;
        short8 b0[4], b1[4];
        for (int ki = 0; ki < 4; ki++) {
            b0[ki] = *(const short8*)(bp + (size_t)j0 * 16 * F + ki * 32);
            b1[ki] = *(const short8*)(bp + (size_t)j1 * 16 * F + ki * 32);
        }
        floatx4 acc0 = {0.f, 0.f, 0.f, 0.f}, acc1 = {0.f, 0.f, 0.f, 0.f};
        for (int ki = 0; ki < 4; ki++)
            acc0 = __builtin_amdgcn_mfma_f32_16x16x32_bf16(a[ki], b0[ki], acc0, 0, 0, 0);
        for (int ki = 0; ki < 4; ki++)
            acc1 = __builtin_amdgcn_mfma_f32_16x16x32_bf16(a[ki], b1[ki], acc1, 0, 0, 0);
        int mb = m0 + msub * 16 + lq * 4;
        for (int pair = 0; pair < 2; pair++) {
            floatx4 ac = pair ? acc1 : acc0;
            int j = pair ? j1 : j0;
            int n = j * 16 + lm;
            if (n < 256) {
                for (int reg = 0; reg < 4; reg++) {
                    int m = mb + reg;
                    if (m < N_NODES)
                        y[(size_t)m * 256 + n] = __float2bfloat16(ac[reg]);
                }
            } else {
                float bv = bias[n - 256];
                for (int reg = 0; reg < 4; reg++) {
                    int m = mb + reg;
                    if (m < N_NODES)
                        z[(size_t)m * F + (n - 256)] = ac[reg] + bv;
                }
            }
        }
    }
}

// ---------------- per-node pull aggregation + relu + residual ----------------
// Fused over both relation segments (contiguous in esrc); mean folded into
// fma weight. Unroll-4 with independent accumulators for memory-level par.
__global__ void k_aggregate(const bf16* __restrict__ y, const float* __restrict__ z,
                            const int* __restrict__ cnt, const int* __restrict__ off,
                            const int* __restrict__ esrc,
                            float* __restrict__ h, float* __restrict__ outp, int layer) {
    int wid = (blockIdx.x * 256 + threadIdx.x) >> 6;
    int lane = threadIdx.x & 63;
    if (wid >= N_NODES) return;
    int n = wid;
    int f = lane * 2;
    int2 cc = *(const int2*)(cnt + n * R);
    int c0 = cc.x, c1 = cc.y;
    int o0 = off[n * R];
    int ctot = c0 + c1;
    float inv0 = (c0 > 0) ? 1.0f / (float)c0 : 0.f;
    float inv1 = (c1 > 0) ? 1.0f / (float)c1 : 0.f;
    const bf16* yb = y + f;
    float s0 = 0.f, s1 = 0.f, t0 = 0.f, t1 = 0.f;
    float u0 = 0.f, u1 = 0.f, v0 = 0.f, v1 = 0.f;
    int i = 0;
    for (; i + 4 <= ctot; i += 4) {
        int sn0 = esrc[o0 + i];
        int sn1 = esrc[o0 + i + 1];
        int sn2 = esrc[o0 + i + 2];
        int sn3 = esrc[o0 + i + 3];
        int ro0 = (i     >= c0) ? 128 : 0; float w0 = (i     >= c0) ? inv1 : inv0;
        int ro1 = (i + 1 >= c0) ? 128 : 0; float w1 = (i + 1 >= c0) ? inv1 : inv0;
        int ro2 = (i + 2 >= c0) ? 128 : 0; float w2 = (i + 2 >= c0) ? inv1 : inv0;
        int ro3 = (i + 3 >= c0) ? 128 : 0; float w3 = (i + 3 >= c0) ? inv1 : inv0;
        __hip_bfloat162 p0 = *(const __hip_bfloat162*)(yb + (size_t)sn0 * 256 + ro0);
        __hip_bfloat162 p1 = *(const __hip_bfloat162*)(yb + (size_t)sn1 * 256 + ro1);
        __hip_bfloat162 p2 = *(const __hip_bfloat162*)(yb + (size_t)sn2 * 256 + ro2);
        __hip_bfloat162 p3 = *(const __hip_bfloat162*)(yb + (size_t)sn3 * 256 + ro3);
        s0 = fmaf(__bfloat162float(p0.x), w0, s0);
        s1 = fmaf(__bfloat162float(p0.y), w0, s1);
        t0 = fmaf(__bfloat162float(p1.x), w1, t0);
        t1 = fmaf(__bfloat162float(p1.y), w1, t1);
        u0 = fmaf(__bfloat162float(p2.x), w2, u0);
        u1 = fmaf(__bfloat162float(p2.y), w2, u1);
        v0 = fmaf(__bfloat162float(p3.x), w3, v0);
        v1 = fmaf(__bfloat162float(p3.y), w3, v1);
    }
    for (; i < ctot; i++) {
        int sn = esrc[o0 + i];
        int ro = (i >= c0) ? 128 : 0;
        float ww = (i >= c0) ? inv1 : inv0;
        __hip_bfloat162 p = *(const __hip_bfloat162*)(yb + (size_t)sn * 256 + ro);
        s0 = fmaf(__bfloat162float(p.x), ww, s0);
        s1 = fmaf(__bfloat162float(p.y), ww, s1);
    }
    float2 zz = *(const float2*)(z + (size_t)n * F + f);
    float a0 = zz.x + ((s0 + t0) + (u0 + v0));
    float a1 = zz.y + ((s1 + t1) + (u1 + v1));
    a0 = fmaxf(a0, 0.f);
    a1 = fmaxf(a1, 0.f);
    if (layer > 0) {
        float2 hp = *(const float2*)(h + (size_t)n * F + f);
        a0 += hp.x; a1 += hp.y;
    }
    float2 o2; o2.x = a0; o2.y = a1;
    *(float2*)(h + (size_t)n * F + f) = o2;
    if (outp) {
        float2 q2; q2.x = a0; q2.y = a1;
        *(float2*)(outp + (size_t)n * F + f) = q2;
    }
}

extern "C" void kernel_launch(void* const* d_in, const int* in_sizes, int n_in,
                              void* d_out, int out_size, void* d_ws, size_t ws_size,
                              hipStream_t stream) {
    const float* x       = (const float*)d_in[0];
    const int*   eidx    = (const int*)d_in[1];
    const int*   etype   = (const int*)d_in[2];
    const float* W0_rel  = (const float*)d_in[3];
    const float* W0_root = (const float*)d_in[4];
    const float* b0      = (const float*)d_in[5];
    const float* Ws_rel  = (const float*)d_in[6];
    const float* Ws_root = (const float*)d_in[7];
    const float* bs      = (const float*)d_in[8];
    const int* src = eidx;
    const int* dst = eidx + N_EDGES;

    char* w = (char*)d_ws;
    float* h   = (float*)w; w += (size_t)N_NODES * F * 4;     // 25.6 MB
    float* z   = (float*)w; w += (size_t)N_NODES * F * 4;     // 25.6 MB
    bf16*  y   = (bf16*)w;  w += (size_t)N_NODES * 256 * 2;   // 25.6 MB
    bf16*  Bt  = (bf16*)w;  w += (size_t)NLAYER * NB * F * 2; // 384 KB
    int* cnt   = (int*)w;   w += (size_t)NSEG * 4;            // contiguous zero region:
    int* fill  = (int*)w;   w += (size_t)NSEG * 4;            //   cnt | fill | stats
    float* stats = (float*)w; w += (size_t)NLAYER * 256 * 4;
    int* off   = (int*)w;   w += (size_t)NSEG * 4;
    int* esrc  = (int*)w;   w += (size_t)N_EDGES * 4;
    int* bsum  = (int*)w;   w += 128 * 4;                     // total ~77 MB

    hipMemsetAsync(cnt, 0, (size_t)NSEG * 4 * 2 + (size_t)NLAYER * 256 * 4, stream);
    k_wt<<<(NLAYER * NB * F + 255) / 256, 256, 0, stream>>>(W0_rel, W0_root, Ws_rel, Ws_root, Bt);
    k_count<<<(N_EDGES + 255) / 256, 256, 0, stream>>>(dst, etype, cnt);
    k_scan1<<<NSCB, 1024, 0, stream>>>(cnt, off, bsum);
    k_scan2<<<1, 128, 0, stream>>>(bsum);
    k_scan3<<<NSCB, 1024, 0, stream>>>(off, bsum);
    k_fill<<<(N_EDGES + 255) / 256, 256, 0, stream>>>(src, dst, etype, off, fill, esrc);

    for (int l = 0; l < NLAYER; l++) {
        float* gs = stats + l * 256;
        const float* bias = (l == 0) ? b0 : (bs + (size_t)(l - 1) * F);
        const float* hin = (l == 0) ? x : h;
        k_bnstats<<<512, 256, 0, stream>>>(hin, gs);
        k_gemm<<<(N_NODES + 63) / 64, 512, 0, stream>>>(
            hin, gs, Bt + (size_t)l * NB * F, bias, y, z);
        k_aggregate<<<(N_NODES * 64 + 255) / 256, 256, 0, stream>>>(
            y, z, cnt, off, esrc, h, (l == 3) ? (float*)d_out : nullptr, l);
    }
}

// Round 7
// 504.602 us; speedup vs baseline: 1.9899x; 1.2367x over previous
//
#include <hip/hip_runtime.h>
#include <hip/hip_bf16.h>

#define N_NODES 50000
#define N_EDGES 600000
#define F 128
#define R 2
#define NLAYER 4
#define NSEG (N_NODES * R)  /* 100000 */
#define NSCB 98             /* scan blocks: ceil(100000/1024) */
#define NB 384              /* gemm out cols: 256 y + 128 z */
#define BN_EPS 1e-5f
#define BETA 1e-4f

typedef __hip_bfloat16 bf16;
typedef __attribute__((ext_vector_type(8))) short short8;  // 8 bf16 (4 VGPRs)
typedef __attribute__((ext_vector_type(4))) float floatx4; // 4 fp32 acc

// ---------------- weight transpose + f32->bf16: Bt[l][j][d] = W[l][d][j] ----------------
// cols j: [0,128)=W_rel[0], [128,256)=W_rel[1], [256,384)=W_root
__global__ void k_wt(const float* __restrict__ W0_rel, const float* __restrict__ W0_root,
                     const float* __restrict__ Ws_rel, const float* __restrict__ Ws_root,
                     bf16* __restrict__ Bt) {
    int idx = blockIdx.x * 256 + threadIdx.x;
    if (idx >= NLAYER * NB * F) return;
    int l = idx / (NB * F);
    int rem = idx % (NB * F);
    int j = rem / F, d = rem % F;
    float v;
    if (j < 256) {
        int r = j >> 7, c = j & 127;
        v = (l == 0) ? W0_rel[(r * F + d) * F + c]
                     : Ws_rel[((size_t)((l - 1) * R + r) * F + d) * F + c];
    } else {
        int c = j - 256;
        v = (l == 0) ? W0_root[d * F + c]
                     : Ws_root[((size_t)(l - 1) * F + d) * F + c];
    }
    Bt[idx] = __float2bfloat16(v);
}

// ---------------- segment counts ----------------
__global__ void k_count(const int* __restrict__ dst, const int* __restrict__ et,
                        int* __restrict__ cnt) {
    int e = blockIdx.x * 256 + threadIdx.x;
    if (e < N_EDGES) atomicAdd(&cnt[dst[e] * R + et[e]], 1);
}

// ---------------- multi-block exclusive scan of cnt ----------------
__global__ void k_scan1(const int* __restrict__ cnt, int* __restrict__ off,
                        int* __restrict__ bsum) {
    int t = threadIdx.x;
    int g = blockIdx.x * 1024 + t;
    int v = (g < NSEG) ? cnt[g] : 0;
    int lane = t & 63;
    int wv = t >> 6;
    int x = v;
    for (int d = 1; d < 64; d <<= 1) {
        int y = __shfl_up(x, d, 64);
        if (lane >= d) x += y;
    }
    __shared__ int wtot[16];
    if (lane == 63) wtot[wv] = x;
    __syncthreads();
    if (t < 16) {
        int s = wtot[t];
        for (int d = 1; d < 16; d <<= 1) {
            int y = __shfl_up(s, d, 64);
            if (t >= d) s += y;
        }
        wtot[t] = s;
    }
    __syncthreads();
    int wpre = (wv == 0) ? 0 : wtot[wv - 1];
    int incl = x + wpre;
    if (g < NSEG) off[g] = incl - v;  // exclusive within block
    if (t == 1023) bsum[blockIdx.x] = incl;
}

__global__ void k_scan2(int* __restrict__ bsum) {
    __shared__ int s[128];
    int t = threadIdx.x;
    int v = (t < NSCB) ? bsum[t] : 0;
    s[t] = v;
    __syncthreads();
    for (int d = 1; d < 128; d <<= 1) {
        int y = (t >= d) ? s[t - d] : 0;
        __syncthreads();
        s[t] += y;
        __syncthreads();
    }
    if (t < NSCB) bsum[t] = s[t] - v;  // exclusive
}

__global__ void k_scan3(int* __restrict__ off, const int* __restrict__ bsum) {
    int g = blockIdx.x * 1024 + threadIdx.x;
    if (g < NSEG) off[g] += bsum[blockIdx.x];
}

// ---------------- fill segment-sorted src list ----------------
__global__ void k_fill(const int* __restrict__ src, const int* __restrict__ dst,
                       const int* __restrict__ et, const int* __restrict__ off,
                       int* __restrict__ fill, int* __restrict__ esrc) {
    int e = blockIdx.x * 256 + threadIdx.x;
    if (e >= N_EDGES) return;
    int seg = dst[e] * R + et[e];
    int idx = off[seg] + atomicAdd(&fill[seg], 1);
    esrc[idx] = src[e];
}

// ---------------- BN column stats: gs[0..127]=sum, gs[128..255]=sumsq ----------------
__global__ void k_bnstats(const float* __restrict__ h, float* __restrict__ gs) {
    int c = threadIdx.x & 127;
    int rl = threadIdx.x >> 7;
    float s = 0.f, q = 0.f;
    for (int r = blockIdx.x * 2 + rl; r < N_NODES; r += gridDim.x * 2) {
        float v = h[(size_t)r * F + c];
        s += v; q += v * v;
    }
    __shared__ float ls[256], lq[256];
    ls[threadIdx.x] = s; lq[threadIdx.x] = q;
    __syncthreads();
    if (rl == 0) {
        atomicAdd(&gs[c], ls[c] + ls[c + 128]);
        atomicAdd(&gs[128 + c], lq[c] + lq[c + 128]);
    }
}

// ---------------- fused BN-apply + GEMM: [y|z] = bn(h) @ [Wr0|Wr1|Wroot] ----------------
// Block = 64-row strip x all 384 cols, 512 threads. A staged once; B staged
// in LDS in 3 chunks of 128 cols. Swapped-operand MFMA (D^T): per lane the
// 4 acc regs are 4 consecutive n at fixed m -> 8B y-stores / 16B z-stores.
__launch_bounds__(512)
__global__ void k_gemm(const float* __restrict__ h, const float* __restrict__ gs,
                       const bf16* __restrict__ Bt, const float* __restrict__ bias,
                       bf16* __restrict__ y, float* __restrict__ z) {
    __shared__ bf16 As[64 * 136];    // 17.4 KB
    __shared__ bf16 Bs[128 * 136];   // 34.8 KB
    int t = threadIdx.x;
    int m0 = blockIdx.x * 64;
    // per-thread BN constants for its 4 fixed columns
    int c4 = (t & 31) * 4;
    float mu[4], rs[4];
    for (int c = 0; c < 4; c++) {
        float mm = gs[c4 + c] * (1.0f / N_NODES);
        float qq = gs[128 + c4 + c] * (1.0f / N_NODES);
        mu[c] = mm;
        rs[c] = rsqrtf(qq - mm * mm + BN_EPS);
    }
    // stage A (BN applied, f32 -> bf16)
    int r0 = t >> 5;  // 0..15
    for (int it = 0; it < 4; it++) {
        int row = r0 + it * 16;
        int m = m0 + row;
        float4 v = {0.f, 0.f, 0.f, 0.f};
        if (m < N_NODES) v = *(const float4*)(h + (size_t)m * F + c4);
        bf16 o[4];
        o[0] = __float2bfloat16((v.x - mu[0]) * rs[0] + BETA);
        o[1] = __float2bfloat16((v.y - mu[1]) * rs[1] + BETA);
        o[2] = __float2bfloat16((v.z - mu[2]) * rs[2] + BETA);
        o[3] = __float2bfloat16((v.w - mu[3]) * rs[3] + BETA);
        *(double*)(As + row * 136 + c4) = *(const double*)o;
    }
    __syncthreads();
    int w = t >> 6;
    int lane = t & 63;
    int msub = w & 3;   // m-subtile 0..3
    int nh = w >> 2;    // n-half of chunk 0..1
    int lm = lane & 15;
    int lq = lane >> 4;
    short8 a[4];
    for (int ki = 0; ki < 4; ki++)
        a[ki] = *(const short8*)(As + (msub * 16 + lm) * 136 + ki * 32 + lq * 8);
    int m = m0 + msub * 16 + lm;
    for (int ci = 0; ci < 3; ci++) {
        __syncthreads();  // previous chunk's Bs readers done
        // stage Bs: Bt rows [ci*128, ci*128+128), fully coalesced
        {
            const bf16* bsrc = Bt + (size_t)ci * 128 * F;
            for (int rr = 0; rr < 4; rr++) {
                int idx = rr * 512 + t;   // 0..2047
                int row = idx >> 4;       // 0..127
                int kc = idx & 15;        // 16-B chunk within row
                short8 v = *(const short8*)(bsrc + row * F + kc * 8);
                *(short8*)(Bs + row * 136 + kc * 8) = v;
            }
        }
        __syncthreads();
        for (int tt = 0; tt < 4; tt++) {
            int nt = nh * 4 + tt;   // n-tile within chunk, 0..7
            short8 b[4];
            for (int ki = 0; ki < 4; ki++)
                b[ki] = *(const short8*)(Bs + (nt * 16 + lm) * 136 + ki * 32 + lq * 8);
            floatx4 acc = {0.f, 0.f, 0.f, 0.f};
            for (int ki = 0; ki < 4; ki++)
                acc = __builtin_amdgcn_mfma_f32_16x16x32_bf16(b[ki], a[ki], acc, 0, 0, 0);
            // D^T: lane holds C[m][n0+reg], n0 = ci*128 + nt*16 + lq*4
            int n0 = ci * 128 + nt * 16 + lq * 4;
            if (m < N_NODES) {
                if (ci < 2) {
                    union { bf16 o[4]; double d; } u;
                    u.o[0] = __float2bfloat16(acc[0]);
                    u.o[1] = __float2bfloat16(acc[1]);
                    u.o[2] = __float2bfloat16(acc[2]);
                    u.o[3] = __float2bfloat16(acc[3]);
                    *(double*)(y + (size_t)m * 256 + n0) = u.d;
                } else {
                    float4 bv = *(const float4*)(bias + (n0 - 256));
                    float4 o4;
                    o4.x = acc[0] + bv.x;
                    o4.y = acc[1] + bv.y;
                    o4.z = acc[2] + bv.z;
                    o4.w = acc[3] + bv.w;
                    *(float4*)(z + (size_t)m * F + (n0 - 256)) = o4;
                }
            }
        }
    }
}

// ---------------- per-node pull aggregation + relu + residual ----------------
// Fused over both relation segments (contiguous in esrc); mean folded into
// fma weight. Unroll-4 with independent accumulators for memory-level par.
__global__ void k_aggregate(const bf16* __restrict__ y, const float* __restrict__ z,
                            const int* __restrict__ cnt, const int* __restrict__ off,
                            const int* __restrict__ esrc,
                            float* __restrict__ h, float* __restrict__ outp, int layer) {
    int wid = (blockIdx.x * 256 + threadIdx.x) >> 6;
    int lane = threadIdx.x & 63;
    if (wid >= N_NODES) return;
    int n = wid;
    int f = lane * 2;
    int2 cc = *(const int2*)(cnt + n * R);
    int c0 = cc.x, c1 = cc.y;
    int o0 = off[n * R];
    int ctot = c0 + c1;
    float inv0 = (c0 > 0) ? 1.0f / (float)c0 : 0.f;
    float inv1 = (c1 > 0) ? 1.0f / (float)c1 : 0.f;
    const bf16* yb = y + f;
    float s0 = 0.f, s1 = 0.f, t0 = 0.f, t1 = 0.f;
    float u0 = 0.f, u1 = 0.f, v0 = 0.f, v1 = 0.f;
    int i = 0;
    for (; i + 4 <= ctot; i += 4) {
        int sn0 = esrc[o0 + i];
        int sn1 = esrc[o0 + i + 1];
        int sn2 = esrc[o0 + i + 2];
        int sn3 = esrc[o0 + i + 3];
        int ro0 = (i     >= c0) ? 128 : 0; float w0 = (i     >= c0) ? inv1 : inv0;
        int ro1 = (i + 1 >= c0) ? 128 : 0; float w1 = (i + 1 >= c0) ? inv1 : inv0;
        int ro2 = (i + 2 >= c0) ? 128 : 0; float w2 = (i + 2 >= c0) ? inv1 : inv0;
        int ro3 = (i + 3 >= c0) ? 128 : 0; float w3 = (i + 3 >= c0) ? inv1 : inv0;
        __hip_bfloat162 p0 = *(const __hip_bfloat162*)(yb + (size_t)sn0 * 256 + ro0);
        __hip_bfloat162 p1 = *(const __hip_bfloat162*)(yb + (size_t)sn1 * 256 + ro1);
        __hip_bfloat162 p2 = *(const __hip_bfloat162*)(yb + (size_t)sn2 * 256 + ro2);
        __hip_bfloat162 p3 = *(const __hip_bfloat162*)(yb + (size_t)sn3 * 256 + ro3);
        s0 = fmaf(__bfloat162float(p0.x), w0, s0);
        s1 = fmaf(__bfloat162float(p0.y), w0, s1);
        t0 = fmaf(__bfloat162float(p1.x), w1, t0);
        t1 = fmaf(__bfloat162float(p1.y), w1, t1);
        u0 = fmaf(__bfloat162float(p2.x), w2, u0);
        u1 = fmaf(__bfloat162float(p2.y), w2, u1);
        v0 = fmaf(__bfloat162float(p3.x), w3, v0);
        v1 = fmaf(__bfloat162float(p3.y), w3, v1);
    }
    for (; i < ctot; i++) {
        int sn = esrc[o0 + i];
        int ro = (i >= c0) ? 128 : 0;
        float ww = (i >= c0) ? inv1 : inv0;
        __hip_bfloat162 p = *(const __hip_bfloat162*)(yb + (size_t)sn * 256 + ro);
        s0 = fmaf(__bfloat162float(p.x), ww, s0);
        s1 = fmaf(__bfloat162float(p.y), ww, s1);
    }
    float2 zz = *(const float2*)(z + (size_t)n * F + f);
    float a0 = zz.x + ((s0 + t0) + (u0 + v0));
    float a1 = zz.y + ((s1 + t1) + (u1 + v1));
    a0 = fmaxf(a0, 0.f);
    a1 = fmaxf(a1, 0.f);
    if (layer > 0) {
        float2 hp = *(const float2*)(h + (size_t)n * F + f);
        a0 += hp.x; a1 += hp.y;
    }
    float2 o2; o2.x = a0; o2.y = a1;
    *(float2*)(h + (size_t)n * F + f) = o2;
    if (outp) {
        float2 q2; q2.x = a0; q2.y = a1;
        *(float2*)(outp + (size_t)n * F + f) = q2;
    }
}

extern "C" void kernel_launch(void* const* d_in, const int* in_sizes, int n_in,
                              void* d_out, int out_size, void* d_ws, size_t ws_size,
                              hipStream_t stream) {
    const float* x       = (const float*)d_in[0];
    const int*   eidx    = (const int*)d_in[1];
    const int*   etype   = (const int*)d_in[2];
    const float* W0_rel  = (const float*)d_in[3];
    const float* W0_root = (const float*)d_in[4];
    const float* b0      = (const float*)d_in[5];
    const float* Ws_rel  = (const float*)d_in[6];
    const float* Ws_root = (const float*)d_in[7];
    const float* bs      = (const float*)d_in[8];
    const int* src = eidx;
    const int* dst = eidx + N_EDGES;

    char* w = (char*)d_ws;
    float* h   = (float*)w; w += (size_t)N_NODES * F * 4;     // 25.6 MB
    float* z   = (float*)w; w += (size_t)N_NODES * F * 4;     // 25.6 MB
    bf16*  y   = (bf16*)w;  w += (size_t)N_NODES * 256 * 2;   // 25.6 MB
    bf16*  Bt  = (bf16*)w;  w += (size_t)NLAYER * NB * F * 2; // 384 KB
    int* cnt   = (int*)w;   w += (size_t)NSEG * 4;            // contiguous zero region:
    int* fill  = (int*)w;   w += (size_t)NSEG * 4;            //   cnt | fill | stats
    float* stats = (float*)w; w += (size_t)NLAYER * 256 * 4;
    int* off   = (int*)w;   w += (size_t)NSEG * 4;
    int* esrc  = (int*)w;   w += (size_t)N_EDGES * 4;
    int* bsum  = (int*)w;   w += 128 * 4;                     // total ~77 MB

    hipMemsetAsync(cnt, 0, (size_t)NSEG * 4 * 2 + (size_t)NLAYER * 256 * 4, stream);
    k_wt<<<(NLAYER * NB * F + 255) / 256, 256, 0, stream>>>(W0_rel, W0_root, Ws_rel, Ws_root, Bt);
    k_count<<<(N_EDGES + 255) / 256, 256, 0, stream>>>(dst, etype, cnt);
    k_scan1<<<NSCB, 1024, 0, stream>>>(cnt, off, bsum);
    k_scan2<<<1, 128, 0, stream>>>(bsum);
    k_scan3<<<NSCB, 1024, 0, stream>>>(off, bsum);
    k_fill<<<(N_EDGES + 255) / 256, 256, 0, stream>>>(src, dst, etype, off, fill, esrc);

    for (int l = 0; l < NLAYER; l++) {
        float* gs = stats + l * 256;
        const float* bias = (l == 0) ? b0 : (bs + (size_t)(l - 1) * F);
        const float* hin = (l == 0) ? x : h;
        k_bnstats<<<512, 256, 0, stream>>>(hin, gs);
        k_gemm<<<(N_NODES + 63) / 64, 512, 0, stream>>>(
            hin, gs, Bt + (size_t)l * NB * F, bias, y, z);
        k_aggregate<<<(N_NODES * 64 + 255) / 256, 256, 0, stream>>>(
            y, z, cnt, off, esrc, h, (l == 3) ? (float*)d_out : nullptr, l);
    }
}

// Round 8
// 487.322 us; speedup vs baseline: 2.0605x; 1.0355x over previous
//
#include <hip/hip_runtime.h>
#include <hip/hip_bf16.h>

#define N_NODES 50000
#define N_EDGES 600000
#define F 128
#define R 2
#define NLAYER 4
#define NSEG (N_NODES * R)  /* 100000 */
#define NSCB 98             /* scan blocks: ceil(100000/1024) */
#define NB 384              /* gemm out cols: 256 y + 128 z */
#define BN_EPS 1e-5f
#define BETA 1e-4f

typedef __hip_bfloat16 bf16;
typedef __attribute__((ext_vector_type(8))) short short8;  // 8 bf16 (4 VGPRs)
typedef __attribute__((ext_vector_type(4))) float floatx4; // 4 fp32 acc

// ---------------- weight transpose + f32->bf16: Bt[l][j][d] = W[l][d][j] ----------------
// cols j: [0,128)=W_rel[0], [128,256)=W_rel[1], [256,384)=W_root
__global__ void k_wt(const float* __restrict__ W0_rel, const float* __restrict__ W0_root,
                     const float* __restrict__ Ws_rel, const float* __restrict__ Ws_root,
                     bf16* __restrict__ Bt) {
    int idx = blockIdx.x * 256 + threadIdx.x;
    if (idx >= NLAYER * NB * F) return;
    int l = idx / (NB * F);
    int rem = idx % (NB * F);
    int j = rem / F, d = rem % F;
    float v;
    if (j < 256) {
        int r = j >> 7, c = j & 127;
        v = (l == 0) ? W0_rel[(r * F + d) * F + c]
                     : Ws_rel[((size_t)((l - 1) * R + r) * F + d) * F + c];
    } else {
        int c = j - 256;
        v = (l == 0) ? W0_root[d * F + c]
                     : Ws_root[((size_t)(l - 1) * F + d) * F + c];
    }
    Bt[idx] = __float2bfloat16(v);
}

// ---------------- segment counts ----------------
__global__ void k_count(const int* __restrict__ dst, const int* __restrict__ et,
                        int* __restrict__ cnt) {
    int e = blockIdx.x * 256 + threadIdx.x;
    if (e < N_EDGES) atomicAdd(&cnt[dst[e] * R + et[e]], 1);
}

// ---------------- multi-block exclusive scan of cnt ----------------
__global__ void k_scan1(const int* __restrict__ cnt, int* __restrict__ off,
                        int* __restrict__ bsum) {
    int t = threadIdx.x;
    int g = blockIdx.x * 1024 + t;
    int v = (g < NSEG) ? cnt[g] : 0;
    int lane = t & 63;
    int wv = t >> 6;
    int x = v;
    for (int d = 1; d < 64; d <<= 1) {
        int y = __shfl_up(x, d, 64);
        if (lane >= d) x += y;
    }
    __shared__ int wtot[16];
    if (lane == 63) wtot[wv] = x;
    __syncthreads();
    if (t < 16) {
        int s = wtot[t];
        for (int d = 1; d < 16; d <<= 1) {
            int y = __shfl_up(s, d, 64);
            if (t >= d) s += y;
        }
        wtot[t] = s;
    }
    __syncthreads();
    int wpre = (wv == 0) ? 0 : wtot[wv - 1];
    int incl = x + wpre;
    if (g < NSEG) off[g] = incl - v;  // exclusive within block
    if (t == 1023) bsum[blockIdx.x] = incl;
}

__global__ void k_scan2(int* __restrict__ bsum) {
    __shared__ int s[128];
    int t = threadIdx.x;
    int v = (t < NSCB) ? bsum[t] : 0;
    s[t] = v;
    __syncthreads();
    for (int d = 1; d < 128; d <<= 1) {
        int y = (t >= d) ? s[t - d] : 0;
        __syncthreads();
        s[t] += y;
        __syncthreads();
    }
    if (t < NSCB) bsum[t] = s[t] - v;  // exclusive
}

__global__ void k_scan3(int* __restrict__ off, const int* __restrict__ bsum) {
    int g = blockIdx.x * 1024 + threadIdx.x;
    if (g < NSEG) off[g] += bsum[blockIdx.x];
}

// ---------------- fill segment-sorted src list ----------------
__global__ void k_fill(const int* __restrict__ src, const int* __restrict__ dst,
                       const int* __restrict__ et, const int* __restrict__ off,
                       int* __restrict__ fill, int* __restrict__ esrc) {
    int e = blockIdx.x * 256 + threadIdx.x;
    if (e >= N_EDGES) return;
    int seg = dst[e] * R + et[e];
    int idx = off[seg] + atomicAdd(&fill[seg], 1);
    esrc[idx] = src[e];
}

// ---------------- BN column stats: gs[0..127]=sum, gs[128..255]=sumsq ----------------
__global__ void k_bnstats(const float* __restrict__ h, float* __restrict__ gs) {
    int c = threadIdx.x & 127;
    int rl = threadIdx.x >> 7;
    float s = 0.f, q = 0.f;
    for (int r = blockIdx.x * 2 + rl; r < N_NODES; r += gridDim.x * 2) {
        float v = h[(size_t)r * F + c];
        s += v; q += v * v;
    }
    __shared__ float ls[256], lq[256];
    ls[threadIdx.x] = s; lq[threadIdx.x] = q;
    __syncthreads();
    if (rl == 0) {
        atomicAdd(&gs[c], ls[c] + ls[c + 128]);
        atomicAdd(&gs[128 + c], lq[c] + lq[c + 128]);
    }
}

// ---------------- fused BN-apply + GEMM: [y|z] = bn(h) @ [Wr0|Wr1|Wroot] ----------------
// Block = 64-row strip x all 384 cols, 512 threads. A staged once; B staged
// in LDS in 3 chunks of 128 cols. Swapped-operand MFMA (D^T): per lane the
// 4 acc regs are 4 consecutive n at fixed m -> 8B y-stores / 16B z-stores.
__launch_bounds__(512)
__global__ void k_gemm(const float* __restrict__ h, const float* __restrict__ gs,
                       const bf16* __restrict__ Bt, const float* __restrict__ bias,
                       bf16* __restrict__ y, float* __restrict__ z) {
    __shared__ bf16 As[64 * 136];    // 17.4 KB
    __shared__ bf16 Bs[128 * 136];   // 34.8 KB
    int t = threadIdx.x;
    int m0 = blockIdx.x * 64;
    // per-thread BN constants for its 4 fixed columns
    int c4 = (t & 31) * 4;
    float mu[4], rs[4];
    for (int c = 0; c < 4; c++) {
        float mm = gs[c4 + c] * (1.0f / N_NODES);
        float qq = gs[128 + c4 + c] * (1.0f / N_NODES);
        mu[c] = mm;
        rs[c] = rsqrtf(qq - mm * mm + BN_EPS);
    }
    // stage A (BN applied, f32 -> bf16)
    int r0 = t >> 5;  // 0..15
    for (int it = 0; it < 4; it++) {
        int row = r0 + it * 16;
        int m = m0 + row;
        float4 v = {0.f, 0.f, 0.f, 0.f};
        if (m < N_NODES) v = *(const float4*)(h + (size_t)m * F + c4);
        bf16 o[4];
        o[0] = __float2bfloat16((v.x - mu[0]) * rs[0] + BETA);
        o[1] = __float2bfloat16((v.y - mu[1]) * rs[1] + BETA);
        o[2] = __float2bfloat16((v.z - mu[2]) * rs[2] + BETA);
        o[3] = __float2bfloat16((v.w - mu[3]) * rs[3] + BETA);
        *(double*)(As + row * 136 + c4) = *(const double*)o;
    }
    __syncthreads();
    int w = t >> 6;
    int lane = t & 63;
    int msub = w & 3;   // m-subtile 0..3
    int nh = w >> 2;    // n-half of chunk 0..1
    int lm = lane & 15;
    int lq = lane >> 4;
    short8 a[4];
    for (int ki = 0; ki < 4; ki++)
        a[ki] = *(const short8*)(As + (msub * 16 + lm) * 136 + ki * 32 + lq * 8);
    int m = m0 + msub * 16 + lm;
    for (int ci = 0; ci < 3; ci++) {
        __syncthreads();  // previous chunk's Bs readers done
        // stage Bs: Bt rows [ci*128, ci*128+128), fully coalesced
        {
            const bf16* bsrc = Bt + (size_t)ci * 128 * F;
            for (int rr = 0; rr < 4; rr++) {
                int idx = rr * 512 + t;   // 0..2047
                int row = idx >> 4;       // 0..127
                int kc = idx & 15;        // 16-B chunk within row
                short8 v = *(const short8*)(bsrc + row * F + kc * 8);
                *(short8*)(Bs + row * 136 + kc * 8) = v;
            }
        }
        __syncthreads();
        for (int tt = 0; tt < 4; tt++) {
            int nt = nh * 4 + tt;   // n-tile within chunk, 0..7
            short8 b[4];
            for (int ki = 0; ki < 4; ki++)
                b[ki] = *(const short8*)(Bs + (nt * 16 + lm) * 136 + ki * 32 + lq * 8);
            floatx4 acc = {0.f, 0.f, 0.f, 0.f};
            for (int ki = 0; ki < 4; ki++)
                acc = __builtin_amdgcn_mfma_f32_16x16x32_bf16(b[ki], a[ki], acc, 0, 0, 0);
            // D^T: lane holds C[m][n0+reg], n0 = ci*128 + nt*16 + lq*4
            int n0 = ci * 128 + nt * 16 + lq * 4;
            if (m < N_NODES) {
                if (ci < 2) {
                    union { bf16 o[4]; double d; } u;
                    u.o[0] = __float2bfloat16(acc[0]);
                    u.o[1] = __float2bfloat16(acc[1]);
                    u.o[2] = __float2bfloat16(acc[2]);
                    u.o[3] = __float2bfloat16(acc[3]);
                    *(double*)(y + (size_t)m * 256 + n0) = u.d;
                } else {
                    float4 bv = *(const float4*)(bias + (n0 - 256));
                    float4 o4;
                    o4.x = acc[0] + bv.x;
                    o4.y = acc[1] + bv.y;
                    o4.z = acc[2] + bv.z;
                    o4.w = acc[3] + bv.w;
                    *(float4*)(z + (size_t)m * F + (n0 - 256)) = o4;
                }
            }
        }
    }
}

// ---------------- per-node pull aggregation + relu + residual ----------------
// Fused over both relation segments; mean folded into fma weight.
// Unroll-8 (+4 +scalar tail) independent gather chains for max MLP.
__global__ void k_aggregate(const bf16* __restrict__ y, const float* __restrict__ z,
                            const int* __restrict__ cnt, const int* __restrict__ off,
                            const int* __restrict__ esrc,
                            float* __restrict__ h, float* __restrict__ outp, int layer) {
    int wid = (blockIdx.x * 256 + threadIdx.x) >> 6;
    int lane = threadIdx.x & 63;
    if (wid >= N_NODES) return;
    int n = wid;
    int f = lane * 2;
    int2 cc = *(const int2*)(cnt + n * R);
    int c0 = cc.x, c1 = cc.y;
    int o0 = off[n * R];
    int ctot = c0 + c1;
    float inv0 = (c0 > 0) ? 1.0f / (float)c0 : 0.f;
    float inv1 = (c1 > 0) ? 1.0f / (float)c1 : 0.f;
    const bf16* yb = y + f;
    // hoist independent loads above the gather loop
    float2 zz = *(const float2*)(z + (size_t)n * F + f);
    float2 hp; hp.x = 0.f; hp.y = 0.f;
    if (layer > 0) hp = *(const float2*)(h + (size_t)n * F + f);
    float sa[8], sb[8];
    #pragma unroll
    for (int k = 0; k < 8; k++) { sa[k] = 0.f; sb[k] = 0.f; }
    int i = 0;
    for (; i + 8 <= ctot; i += 8) {
        int sn[8];
        #pragma unroll
        for (int k = 0; k < 8; k++) sn[k] = esrc[o0 + i + k];
        __hip_bfloat162 p[8];
        #pragma unroll
        for (int k = 0; k < 8; k++) {
            int ro = (i + k >= c0) ? 128 : 0;
            p[k] = *(const __hip_bfloat162*)(yb + (size_t)sn[k] * 256 + ro);
        }
        #pragma unroll
        for (int k = 0; k < 8; k++) {
            float wk = (i + k >= c0) ? inv1 : inv0;
            sa[k] = fmaf(__bfloat162float(p[k].x), wk, sa[k]);
            sb[k] = fmaf(__bfloat162float(p[k].y), wk, sb[k]);
        }
    }
    if (i + 4 <= ctot) {
        int sn[4];
        #pragma unroll
        for (int k = 0; k < 4; k++) sn[k] = esrc[o0 + i + k];
        __hip_bfloat162 p[4];
        #pragma unroll
        for (int k = 0; k < 4; k++) {
            int ro = (i + k >= c0) ? 128 : 0;
            p[k] = *(const __hip_bfloat162*)(yb + (size_t)sn[k] * 256 + ro);
        }
        #pragma unroll
        for (int k = 0; k < 4; k++) {
            float wk = (i + k >= c0) ? inv1 : inv0;
            sa[k] = fmaf(__bfloat162float(p[k].x), wk, sa[k]);
            sb[k] = fmaf(__bfloat162float(p[k].y), wk, sb[k]);
        }
        i += 4;
    }
    for (; i < ctot; i++) {
        int sn = esrc[o0 + i];
        int ro = (i >= c0) ? 128 : 0;
        float wk = (i >= c0) ? inv1 : inv0;
        __hip_bfloat162 p = *(const __hip_bfloat162*)(yb + (size_t)sn * 256 + ro);
        sa[0] = fmaf(__bfloat162float(p.x), wk, sa[0]);
        sb[0] = fmaf(__bfloat162float(p.y), wk, sb[0]);
    }
    float a0 = zz.x + (((sa[0] + sa[1]) + (sa[2] + sa[3])) + ((sa[4] + sa[5]) + (sa[6] + sa[7])));
    float a1 = zz.y + (((sb[0] + sb[1]) + (sb[2] + sb[3])) + ((sb[4] + sb[5]) + (sb[6] + sb[7])));
    a0 = fmaxf(a0, 0.f);
    a1 = fmaxf(a1, 0.f);
    a0 += hp.x;
    a1 += hp.y;
    float2 o2; o2.x = a0; o2.y = a1;
    *(float2*)(h + (size_t)n * F + f) = o2;
    if (outp) {
        float2 q2; q2.x = a0; q2.y = a1;
        *(float2*)(outp + (size_t)n * F + f) = q2;
    }
}

extern "C" void kernel_launch(void* const* d_in, const int* in_sizes, int n_in,
                              void* d_out, int out_size, void* d_ws, size_t ws_size,
                              hipStream_t stream) {
    const float* x       = (const float*)d_in[0];
    const int*   eidx    = (const int*)d_in[1];
    const int*   etype   = (const int*)d_in[2];
    const float* W0_rel  = (const float*)d_in[3];
    const float* W0_root = (const float*)d_in[4];
    const float* b0      = (const float*)d_in[5];
    const float* Ws_rel  = (const float*)d_in[6];
    const float* Ws_root = (const float*)d_in[7];
    const float* bs      = (const float*)d_in[8];
    const int* src = eidx;
    const int* dst = eidx + N_EDGES;

    char* w = (char*)d_ws;
    float* h   = (float*)w; w += (size_t)N_NODES * F * 4;     // 25.6 MB
    float* z   = (float*)w; w += (size_t)N_NODES * F * 4;     // 25.6 MB
    bf16*  y   = (bf16*)w;  w += (size_t)N_NODES * 256 * 2;   // 25.6 MB
    bf16*  Bt  = (bf16*)w;  w += (size_t)NLAYER * NB * F * 2; // 384 KB
    int* cnt   = (int*)w;   w += (size_t)NSEG * 4;            // contiguous zero region:
    int* fill  = (int*)w;   w += (size_t)NSEG * 4;            //   cnt | fill | stats
    float* stats = (float*)w; w += (size_t)NLAYER * 256 * 4;
    int* off   = (int*)w;   w += (size_t)NSEG * 4;
    int* esrc  = (int*)w;   w += (size_t)N_EDGES * 4;
    int* bsum  = (int*)w;   w += 128 * 4;                     // total ~77 MB

    hipMemsetAsync(cnt, 0, (size_t)NSEG * 4 * 2 + (size_t)NLAYER * 256 * 4, stream);
    k_wt<<<(NLAYER * NB * F + 255) / 256, 256, 0, stream>>>(W0_rel, W0_root, Ws_rel, Ws_root, Bt);
    k_count<<<(N_EDGES + 255) / 256, 256, 0, stream>>>(dst, etype, cnt);
    k_scan1<<<NSCB, 1024, 0, stream>>>(cnt, off, bsum);
    k_scan2<<<1, 128, 0, stream>>>(bsum);
    k_scan3<<<NSCB, 1024, 0, stream>>>(off, bsum);
    k_fill<<<(N_EDGES + 255) / 256, 256, 0, stream>>>(src, dst, etype, off, fill, esrc);

    for (int l = 0; l < NLAYER; l++) {
        float* gs = stats + l * 256;
        const float* bias = (l == 0) ? b0 : (bs + (size_t)(l - 1) * F);
        const float* hin = (l == 0) ? x : h;
        k_bnstats<<<512, 256, 0, stream>>>(hin, gs);
        k_gemm<<<(N_NODES + 63) / 64, 512, 0, stream>>>(
            hin, gs, Bt + (size_t)l * NB * F, bias, y, z);
        k_aggregate<<<(N_NODES * 64 + 255) / 256, 256, 0, stream>>>(
            y, z, cnt, off, esrc, h, (l == 3) ? (float*)d_out : nullptr, l);
    }
}